// Round 1
// baseline (1053.339 us; speedup 1.0000x reference)
//
#include <hip/hip_runtime.h>
#include <cstdint>
#include <cstddef>

#define E_    100
#define N_    50
#define B_    8192
#define L_    1000
#define NPAIR 4950

// ---------------- K0a: tiny precomputes (attention u/c vectors, bias copies, pair table, vv) ----
__global__ __launch_bounds__(256) void k0a(const float* __restrict__ v,
        const float* __restrict__ W1, const float* __restrict__ b1, const float* __restrict__ W2,
        const float* __restrict__ W3, const float* __restrict__ b3, const float* __restrict__ W4,
        const float* __restrict__ b5, const float* __restrict__ b6, const float* __restrict__ b7,
        float* __restrict__ usf, float* __restrict__ csf,
        float* __restrict__ b5f, float* __restrict__ b6f, float* __restrict__ b7f,
        float* __restrict__ vvp, int* __restrict__ pairIJ) {
    int tid = threadIdx.x;
    if (tid < 200) {
        int h = (tid >= 100); int e = tid - 100 * h;
        const float* Wa = h ? W3 : W1; const float* Wb = h ? W4 : W2;
        float u = 0.f;
        for (int t = 0; t < 8; t++) u += Wa[t * 100 + e] * Wb[t];
        usf[tid] = u;
    } else if (tid < 202) {
        int h = tid - 200;
        const float* bb = h ? b3 : b1; const float* Wb = h ? W4 : W2;
        float c = 0.f;
        for (int t = 0; t < 8; t++) c += bb[t] * Wb[t];
        csf[h] = c;
    }
    if (tid < 100) {
        b5f[tid] = b5[tid];
        b6f[tid] = b6[tid];
        b7f[tid] = b7[tid];
        int i = tid;
        int base = i * 99 - (i * (i - 1)) / 2;  // start of triu row i (k=1), i-major
        float vi0 = v[i * 4 + 0], vi1 = v[i * 4 + 1];
        float vi2 = v[i * 4 + 2], vi3 = v[i * 4 + 3];
        for (int j = i + 1; j < 100; j++) {
            int p = base + (j - i - 1);
            pairIJ[p] = (i << 8) | j;
            vvp[p] = vi0 * v[j * 4 + 0] + vi1 * v[j * 4 + 1]
                   + vi2 * v[j * 4 + 2] + vi3 * v[j * 4 + 3];
        }
    }
}

// ---------------- K0b: transpose W5,W6,W8 ----------------
__global__ __launch_bounds__(256) void k0b(const float* __restrict__ W5, const float* __restrict__ W6,
        const float* __restrict__ W8, float* __restrict__ W5fT, float* __restrict__ W6fT,
        float* __restrict__ W8fT) {
    int gid = blockIdx.x * 256 + threadIdx.x;
    if (gid < 20000) {                       // W5fT[j][t] = W5[t][j], j<200,t<100
        int o = gid; int j = o / 100; int t = o - 100 * j;
        W5fT[o] = W5[t * 200 + j];
    } else if (gid < 30000) {                // W6fT[j][t] = W6[t][j]
        int o = gid - 20000; int j = o / 100; int t = o - 100 * j;
        W6fT[o] = W6[t * 100 + j];
    } else if (gid < 50000) {                // W8fT[e][u] = W8[u][e], e<200,u<100
        int o = gid - 30000; int e = o / 100; int u = o - 100 * e;
        W8fT[o] = W8[u * 200 + e];
    }
}

// ---------------- K0c: bl8f[l] = sum_u b8[u]*le[u][l];  c8f[u] = sum_t b7[t]*W8[u][100+t] ----
__global__ __launch_bounds__(256) void k0c(const float* __restrict__ b8, const float* __restrict__ le,
                                           const float* __restrict__ b7, const float* __restrict__ W8,
                                           float* __restrict__ bl8f, float* __restrict__ c8f) {
    int gid = blockIdx.x * 256 + threadIdx.x;
    if (gid < L_) {
        float acc = 0.f;
        for (int u = 0; u < 100; u++) acc += b8[u] * le[u * 1000 + gid];
        bl8f[gid] = acc;
    } else if (gid < L_ + 100) {
        int u = gid - L_;
        float acc = 0.f;
        for (int t = 0; t < 100; t++) acc += b7[t] * W8[u * 200 + 100 + t];
        c8f[u] = acc;
    }
}

// ---------------- K0d: W7fT[p][k] = W7[k][p] * vvp[p] (transposed, vv folded) ----------------
__global__ __launch_bounds__(256) void k0d(const float* __restrict__ W7, const float* __restrict__ vvp,
                                           float* __restrict__ W7fT) {
    __shared__ float tile[100 * 65];
    __shared__ float vvs[64];
    int p0 = blockIdx.x * 64;
    int tid = threadIdx.x; int pl = tid & 63;
    int pcnt = min(64, NPAIR - p0);
    if (tid < 64) vvs[tid] = (p0 + tid < NPAIR) ? vvp[p0 + tid] : 0.f;
    __syncthreads();
    for (int kk = tid >> 6; kk < 100; kk += 4) {
        float w = (pl < pcnt) ? W7[kk * NPAIR + p0 + pl] : 0.f;
        tile[kk * 65 + pl] = w * vvs[pl];
    }
    __syncthreads();
    for (int o = tid; o < 6400; o += 256) {
        int pp = o / 100; int k = o - 100 * pp;
        if (pp < pcnt) W7fT[(size_t)(p0 + pp) * 100 + k] = tile[k * 65 + pp];
    }
}

// ---------------- K1: attention pools -> cat1[B][200] ----------------
__global__ __launch_bounds__(256) void k1(const float* __restrict__ x, const float* __restrict__ usf,
                                          const float* __restrict__ csf, float* __restrict__ cat1) {
    __shared__ float xs[N_ * 101];
    __shared__ float zs[2][64];
    __shared__ float wsm[2][64];
    __shared__ float uss[200];
    __shared__ float css[2];
    int b = blockIdx.x; int tid = threadIdx.x;
    const float* xr = x + (size_t)b * (N_ * E_);
    for (int li = tid; li < (N_ * E_) / 4; li += 256) {   // 1250 float4s
        float4 vv = ((const float4*)xr)[li];
        int flat = li * 4; int n = flat / 100; int e = flat - n * 100;
        float* d = xs + n * 101 + e;                       // e<=96, stays in row
        d[0] = vv.x; d[1] = vv.y; d[2] = vv.z; d[3] = vv.w;
    }
    if (tid < 200) uss[tid] = usf[tid];
    if (tid < 2) css[tid] = csf[tid];
    __syncthreads();
    if (tid < 100) {
        int h = (tid >= 50); int n = tid - 50 * h;
        float z = css[h];
        const float* u = uss + h * 100;
        for (int e = 0; e < 100; e++) z = fmaf(xs[n * 101 + e], u[e], z);
        zs[h][n] = expf(z);          // logits = exp(h @ W2^T)
    }
    __syncthreads();
    int wv = tid >> 6, ln = tid & 63;
    if (wv < 2) {
        float a = (ln < 50) ? zs[wv][ln] : -3.0e38f;
        float m = a;
        for (int s = 1; s < 64; s <<= 1) m = fmaxf(m, __shfl_xor(m, s, 64));
        float ex = (ln < 50) ? expf(a - m) : 0.f;
        float ss = ex;
        for (int s = 1; s < 64; s <<= 1) ss += __shfl_xor(ss, s, 64);
        if (ln < 50) wsm[wv][ln] = ex / ss;   // softmax over N
    }
    __syncthreads();
    if (tid < 200) {
        int h = (tid >= 100); int e = tid - 100 * h;
        float q = 0.f;
        for (int n = 0; n < 50; n++) q = fmaf(xs[n * 101 + e], wsm[h][n], q);
        cat1[(size_t)b * 200 + tid] = q;      // [q1 | q2]
    }
}

// ---------------- K2: h5, h6, cross-feature x W7 ----------------
// Weight streams now go through per-lane vector loads (in-order vmcnt, pipelined),
// NOT wave-uniform s_load (out-of-order scalar returns force lgkmcnt(0) drains each
// iteration when mixed with ds_read -> the 16.7% VALUBusy stall).
// k-slices are 28 wide at {0,28,56,72} so every float4 weight load is 16B-aligned
// against the unpadded [*][100] layouts; the 72..83 overlap is computed bitwise
// identically by two waves (benign duplicate LDS/global writes).
__global__ __launch_bounds__(256, 2) void k2(const float* __restrict__ cat1,
        const float* __restrict__ W5fT, const float* __restrict__ W6fT,
        const float* __restrict__ b5f, const float* __restrict__ b6f,
        const float* __restrict__ W7fT, const int* __restrict__ pairIJ,
        float* __restrict__ h6T, float* __restrict__ h7Tp) {
    __shared__ float h5s[64 * 101];
    __shared__ int pij[1240];
    const int g  = blockIdx.x >> 7;          // pair group 0..3
    const int rb = blockIdx.x & 127;
    const int r0 = rb * 64;
    const int tid = threadIdx.x;
    const int lane = tid & 63;
    const int w = tid >> 6;
    const int kbase = (w < 3) ? w * 28 : 72;   // divergent-looking -> vector loads

    float acc[28];

    // ---- phase A: h5 = cat1 @ W5^T + b5 (per-lane row stream of cat1) ----
    {
        const float4* bp = (const float4*)(b5f + kbase);
        #pragma unroll
        for (int q = 0; q < 7; q++) {
            float4 t = bp[q];
            acc[4*q] = t.x; acc[4*q+1] = t.y; acc[4*q+2] = t.z; acc[4*q+3] = t.w;
        }
    }
    const float* xr = cat1 + (size_t)(r0 + lane) * 200;
    for (int j = 0; j < 200; j += 4) {
        float4 xv = *(const float4*)(xr + j);
        float xe[4] = {xv.x, xv.y, xv.z, xv.w};
        #pragma unroll
        for (int jj = 0; jj < 4; jj++) {
            const float4* wp = (const float4*)(W5fT + (j + jj) * 100 + kbase);
            float xs = xe[jj];
            #pragma unroll
            for (int q = 0; q < 7; q++) {
                float4 wv = wp[q];
                acc[4*q]   = fmaf(xs, wv.x, acc[4*q]);
                acc[4*q+1] = fmaf(xs, wv.y, acc[4*q+1]);
                acc[4*q+2] = fmaf(xs, wv.z, acc[4*q+2]);
                acc[4*q+3] = fmaf(xs, wv.w, acc[4*q+3]);
            }
        }
    }
    #pragma unroll
    for (int m = 0; m < 28; m++) h5s[lane * 101 + kbase + m] = acc[m];

    const int pstart = g * 1238;
    const int np = min(NPAIR, pstart + 1238) - pstart;
    for (int o = tid; o < np; o += 256) pij[o] = pairIJ[pstart + o];
    __syncthreads();

    // ---- phase B: h6 = h5 @ W6^T + b6 (group 0 only) ----
    if (g == 0) {
        {
            const float4* bp = (const float4*)(b6f + kbase);
            #pragma unroll
            for (int q = 0; q < 7; q++) {
                float4 t = bp[q];
                acc[4*q] = t.x; acc[4*q+1] = t.y; acc[4*q+2] = t.z; acc[4*q+3] = t.w;
            }
        }
        #pragma unroll 2
        for (int j = 0; j < 100; j++) {
            float hv = h5s[lane * 101 + j];
            const float4* wp = (const float4*)(W6fT + j * 100 + kbase);
            #pragma unroll
            for (int q = 0; q < 7; q++) {
                float4 wv = wp[q];
                acc[4*q]   = fmaf(hv, wv.x, acc[4*q]);
                acc[4*q+1] = fmaf(hv, wv.y, acc[4*q+1]);
                acc[4*q+2] = fmaf(hv, wv.z, acc[4*q+2]);
                acc[4*q+3] = fmaf(hv, wv.w, acc[4*q+3]);
            }
        }
        #pragma unroll
        for (int m = 0; m < 28; m++) h6T[(size_t)(kbase + m) * B_ + r0 + lane] = acc[m];
    }

    // ---- phase C: h7 partial over this group's pairs (2-deep pipelined weight stream) ----
    #pragma unroll
    for (int m = 0; m < 28; m++) acc[m] = 0.f;
    const float* wb = W7fT + (size_t)pstart * 100 + kbase;
    const int hbase = lane * 101;
    float4 wA[7], wB[7];
    {
        const float4* wp = (const float4*)wb;
        #pragma unroll
        for (int q = 0; q < 7; q++) wA[q] = wp[q];
    }
    int pl = 0;
    for (; pl + 2 <= np; pl += 2) {
        {
            const float4* wp = (const float4*)(wb + (size_t)(pl + 1) * 100);
            #pragma unroll
            for (int q = 0; q < 7; q++) wB[q] = wp[q];
        }
        int ij = pij[pl];
        float cf = h5s[hbase + (ij >> 8)] * h5s[hbase + (ij & 255)];
        #pragma unroll
        for (int q = 0; q < 7; q++) {
            acc[4*q]   = fmaf(cf, wA[q].x, acc[4*q]);
            acc[4*q+1] = fmaf(cf, wA[q].y, acc[4*q+1]);
            acc[4*q+2] = fmaf(cf, wA[q].z, acc[4*q+2]);
            acc[4*q+3] = fmaf(cf, wA[q].w, acc[4*q+3]);
        }
        if (pl + 2 < np) {
            const float4* wp = (const float4*)(wb + (size_t)(pl + 2) * 100);
            #pragma unroll
            for (int q = 0; q < 7; q++) wA[q] = wp[q];
        }
        int ij2 = pij[pl + 1];
        float cf2 = h5s[hbase + (ij2 >> 8)] * h5s[hbase + (ij2 & 255)];
        #pragma unroll
        for (int q = 0; q < 7; q++) {
            acc[4*q]   = fmaf(cf2, wB[q].x, acc[4*q]);
            acc[4*q+1] = fmaf(cf2, wB[q].y, acc[4*q+1]);
            acc[4*q+2] = fmaf(cf2, wB[q].z, acc[4*q+2]);
            acc[4*q+3] = fmaf(cf2, wB[q].w, acc[4*q+3]);
        }
    }
    if (pl < np) {
        int ij = pij[pl];
        float cf = h5s[hbase + (ij >> 8)] * h5s[hbase + (ij & 255)];
        #pragma unroll
        for (int q = 0; q < 7; q++) {
            acc[4*q]   = fmaf(cf, wA[q].x, acc[4*q]);
            acc[4*q+1] = fmaf(cf, wA[q].y, acc[4*q+1]);
            acc[4*q+2] = fmaf(cf, wA[q].z, acc[4*q+2]);
            acc[4*q+3] = fmaf(cf, wA[q].w, acc[4*q+3]);
        }
    }
    float* h7p = h7Tp + (size_t)g * 100 * B_;
    #pragma unroll
    for (int m = 0; m < 28; m++)
        h7p[(size_t)(kbase + m) * B_ + r0 + lane] = acc[m];
}

// ---------------- K3a: h8T = W8 @ [h6; sum(h7 partials)] + c8 ----------------
// 8 waves: (w&3) -> 28-wide u-slice {0,28,56,72}; (w>>2) -> e-half (0..99 / 100..199).
// b7 contribution is the precomputed c8f. Halves combined through LDS.
__global__ __launch_bounds__(512, 2) void k3a(const float* __restrict__ h6T, const float* __restrict__ h7Tp,
        const float* __restrict__ c8f, const float* __restrict__ W8fT, float* __restrict__ h8T) {
    __shared__ float part[100 * 64];
    int tid = threadIdx.x;
    int lane = tid & 63;
    int w = tid >> 6;
    int ws_ = w & 3;
    int half = w >> 2;
    int ubase = (ws_ < 3) ? ws_ * 28 : 72;
    int b = blockIdx.x * 64 + lane;
    float acc[28];
    if (half) {
        const float4* cp = (const float4*)(c8f + ubase);
        #pragma unroll
        for (int q = 0; q < 7; q++) {
            float4 t = cp[q];
            acc[4*q] = t.x; acc[4*q+1] = t.y; acc[4*q+2] = t.z; acc[4*q+3] = t.w;
        }
    } else {
        #pragma unroll
        for (int m = 0; m < 28; m++) acc[m] = 0.f;
    }
    const float* wb = W8fT + (half ? 10000 : 0) + ubase;
    #pragma unroll 2
    for (int e = 0; e < 100; e++) {
        float vv;
        if (half) {
            vv = h7Tp[(size_t)e * B_ + b]
               + h7Tp[(size_t)(100 + e) * B_ + b]
               + h7Tp[(size_t)(200 + e) * B_ + b]
               + h7Tp[(size_t)(300 + e) * B_ + b];
        } else {
            vv = h6T[(size_t)e * B_ + b];
        }
        const float4* wp = (const float4*)(wb + e * 100);
        #pragma unroll
        for (int q = 0; q < 7; q++) {
            float4 wv = wp[q];
            acc[4*q]   = fmaf(vv, wv.x, acc[4*q]);
            acc[4*q+1] = fmaf(vv, wv.y, acc[4*q+1]);
            acc[4*q+2] = fmaf(vv, wv.z, acc[4*q+2]);
            acc[4*q+3] = fmaf(vv, wv.w, acc[4*q+3]);
        }
    }
    if (half) {
        #pragma unroll
        for (int m = 0; m < 28; m++) part[(ubase + m) * 64 + lane] = acc[m];
    }
    __syncthreads();
    if (!half) {
        #pragma unroll
        for (int m = 0; m < 28; m++)
            h8T[(size_t)(ubase + m) * B_ + b] = acc[m] + part[(ubase + m) * 64 + lane];
    }
}

// ---------------- K3b: out = h8 @ label_embedding (+ b8@le folded bias) ----------------
__global__ __launch_bounds__(256) void k3b(const float* __restrict__ h8T, const float* __restrict__ le,
        const float* __restrict__ bl8f, float* __restrict__ out) {
    int lq = blockIdx.x & 3; int bb = blockIdx.x >> 2;
    int b0 = bb * 32;
    int l = lq * 256 + threadIdx.x;
    bool valid = (l < L_);
    int lc = valid ? l : 0;
    unsigned off0 = 0;
    asm volatile("" : "+v"(off0));           // opaque zero in a VGPR: defeat uniform-addr scalarization
    const float* hb = h8T + b0 + off0;
    float acc[32];
    #pragma unroll
    for (int i = 0; i < 32; i++) acc[i] = 0.f;
    #pragma unroll 2
    for (int u = 0; u < 100; u++) {
        float lev = le[u * 1000 + lc];
        const float4* hp = (const float4*)(hb + (size_t)u * B_);
        #pragma unroll
        for (int q = 0; q < 8; q++) {
            float4 hv = hp[q];
            acc[4*q]   = fmaf(hv.x, lev, acc[4*q]);
            acc[4*q+1] = fmaf(hv.y, lev, acc[4*q+1]);
            acc[4*q+2] = fmaf(hv.z, lev, acc[4*q+2]);
            acc[4*q+3] = fmaf(hv.w, lev, acc[4*q+3]);
        }
    }
    if (valid) {
        float bias = bl8f[l];
        #pragma unroll
        for (int i = 0; i < 32; i++)
            out[(size_t)(b0 + i) * 1000 + l] = acc[i] + bias;
    }
}

extern "C" void kernel_launch(void* const* d_in, const int* in_sizes, int n_in,
                              void* d_out, int out_size, void* d_ws, size_t ws_size,
                              hipStream_t stream) {
    const float* x  = (const float*)d_in[0];
    const float* v  = (const float*)d_in[1];
    const float* W1 = (const float*)d_in[2];
    const float* b1 = (const float*)d_in[3];
    const float* W2 = (const float*)d_in[4];
    const float* W3 = (const float*)d_in[5];
    const float* b3 = (const float*)d_in[6];
    const float* W4 = (const float*)d_in[7];
    const float* W5 = (const float*)d_in[8];
    const float* b5 = (const float*)d_in[9];
    const float* W6 = (const float*)d_in[10];
    const float* b6 = (const float*)d_in[11];
    const float* W7 = (const float*)d_in[12];
    const float* b7 = (const float*)d_in[13];
    const float* W8 = (const float*)d_in[14];
    const float* b8 = (const float*)d_in[15];
    const float* le = (const float*)d_in[16];
    float* out = (float*)d_out;
    float* ws = (float*)d_ws;

    float* cat1   = ws;                 // 1,638,400
    float* h6T    = ws + 1638400;       //   819,200
    float* h7Tp   = ws + 2457600;       // 3,276,800 (4 partials x 100 x B)
    float* h8T    = ws + 5734400;       //   819,200
    float* W7fT   = ws + 6553600;       //   495,000
    float* W5fT   = ws + 7048600;       //    20,000
    float* W6fT   = ws + 7068600;       //    10,000
    float* W8fT   = ws + 7078600;       //    20,000
    float* usf    = ws + 7098600;       //       200
    float* csf    = ws + 7098800;       //       2 (+2 pad)
    float* b5f    = ws + 7098804;       //       100
    float* b6f    = ws + 7098904;       //       100
    float* b7f    = ws + 7099004;       //       100
    float* bl8f   = ws + 7099104;       //      1000
    float* vvp    = ws + 7100104;       //      4950
    int*   pairIJ = (int*)(ws + 7105054); //    4950
    float* c8f    = ws + 7110004;       //       100

    k0a<<<1, 256, 0, stream>>>(v, W1, b1, W2, W3, b3, W4, b5, b6, b7,
                               usf, csf, b5f, b6f, b7f, vvp, pairIJ);
    k0b<<<196, 256, 0, stream>>>(W5, W6, W8, W5fT, W6fT, W8fT);
    k0c<<<5, 256, 0, stream>>>(b8, le, b7, W8, bl8f, c8f);
    k0d<<<78, 256, 0, stream>>>(W7, vvp, W7fT);
    k1<<<8192, 256, 0, stream>>>(x, usf, csf, cat1);
    k2<<<512, 256, 0, stream>>>(cat1, W5fT, W6fT, b5f, b6f, W7fT, pairIJ, h6T, h7Tp);
    k3a<<<128, 512, 0, stream>>>(h6T, h7Tp, c8f, W8fT, h8T);
    k3b<<<1024, 256, 0, stream>>>(h8T, le, bl8f, out);
}

// Round 2
// 788.582 us; speedup vs baseline: 1.3357x; 1.3357x over previous
//
#include <hip/hip_runtime.h>
#include <cstdint>
#include <cstddef>

#define E_    100
#define N_    50
#define B_    8192
#define L_    1000
#define NPAIR 4950

// ---------------- K0a: tiny precomputes (attention u/c vectors, bias copies, pair table, vv) ----
__global__ __launch_bounds__(256) void k0a(const float* __restrict__ v,
        const float* __restrict__ W1, const float* __restrict__ b1, const float* __restrict__ W2,
        const float* __restrict__ W3, const float* __restrict__ b3, const float* __restrict__ W4,
        const float* __restrict__ b5, const float* __restrict__ b6, const float* __restrict__ b7,
        float* __restrict__ usf, float* __restrict__ csf,
        float* __restrict__ b5f, float* __restrict__ b6f, float* __restrict__ b7f,
        float* __restrict__ vvp, int* __restrict__ pairIJ) {
    int tid = threadIdx.x;
    if (tid < 200) {
        int h = (tid >= 100); int e = tid - 100 * h;
        const float* Wa = h ? W3 : W1; const float* Wb = h ? W4 : W2;
        float u = 0.f;
        for (int t = 0; t < 8; t++) u += Wa[t * 100 + e] * Wb[t];
        usf[tid] = u;
    } else if (tid < 202) {
        int h = tid - 200;
        const float* bb = h ? b3 : b1; const float* Wb = h ? W4 : W2;
        float c = 0.f;
        for (int t = 0; t < 8; t++) c += bb[t] * Wb[t];
        csf[h] = c;
    }
    if (tid < 100) {
        b5f[tid] = b5[tid];
        b6f[tid] = b6[tid];
        b7f[tid] = b7[tid];
        int i = tid;
        int base = i * 99 - (i * (i - 1)) / 2;  // start of triu row i (k=1), i-major
        float vi0 = v[i * 4 + 0], vi1 = v[i * 4 + 1];
        float vi2 = v[i * 4 + 2], vi3 = v[i * 4 + 3];
        for (int j = i + 1; j < 100; j++) {
            int p = base + (j - i - 1);
            pairIJ[p] = (i << 8) | j;
            vvp[p] = vi0 * v[j * 4 + 0] + vi1 * v[j * 4 + 1]
                   + vi2 * v[j * 4 + 2] + vi3 * v[j * 4 + 3];
        }
    }
}

// ---------------- K0b: transpose W5,W6,W8 ----------------
__global__ __launch_bounds__(256) void k0b(const float* __restrict__ W5, const float* __restrict__ W6,
        const float* __restrict__ W8, float* __restrict__ W5fT, float* __restrict__ W6fT,
        float* __restrict__ W8fT) {
    int gid = blockIdx.x * 256 + threadIdx.x;
    if (gid < 20000) {                       // W5fT[j][t] = W5[t][j], j<200,t<100
        int o = gid; int j = o / 100; int t = o - 100 * j;
        W5fT[o] = W5[t * 200 + j];
    } else if (gid < 30000) {                // W6fT[j][t] = W6[t][j]
        int o = gid - 20000; int j = o / 100; int t = o - 100 * j;
        W6fT[o] = W6[t * 100 + j];
    } else if (gid < 50000) {                // W8fT[e][u] = W8[u][e], e<200,u<100
        int o = gid - 30000; int e = o / 100; int u = o - 100 * e;
        W8fT[o] = W8[u * 200 + e];
    }
}

// ---------------- K0c: bl8f[l] = sum_u b8[u]*le[u][l];  c8f[u] = sum_t b7[t]*W8[u][100+t] ----
__global__ __launch_bounds__(256) void k0c(const float* __restrict__ b8, const float* __restrict__ le,
                                           const float* __restrict__ b7, const float* __restrict__ W8,
                                           float* __restrict__ bl8f, float* __restrict__ c8f) {
    int gid = blockIdx.x * 256 + threadIdx.x;
    if (gid < L_) {
        float acc = 0.f;
        for (int u = 0; u < 100; u++) acc += b8[u] * le[u * 1000 + gid];
        bl8f[gid] = acc;
    } else if (gid < L_ + 100) {
        int u = gid - L_;
        float acc = 0.f;
        for (int t = 0; t < 100; t++) acc += b7[t] * W8[u * 200 + 100 + t];
        c8f[u] = acc;
    }
}

// ---------------- K0d: W7fT[p][k] = W7[k][p] * vvp[p] (transposed, vv folded) ----------------
__global__ __launch_bounds__(256) void k0d(const float* __restrict__ W7, const float* __restrict__ vvp,
                                           float* __restrict__ W7fT) {
    __shared__ float tile[100 * 65];
    __shared__ float vvs[64];
    int p0 = blockIdx.x * 64;
    int tid = threadIdx.x; int pl = tid & 63;
    int pcnt = min(64, NPAIR - p0);
    if (tid < 64) vvs[tid] = (p0 + tid < NPAIR) ? vvp[p0 + tid] : 0.f;
    __syncthreads();
    for (int kk = tid >> 6; kk < 100; kk += 4) {
        float w = (pl < pcnt) ? W7[kk * NPAIR + p0 + pl] : 0.f;
        tile[kk * 65 + pl] = w * vvs[pl];
    }
    __syncthreads();
    for (int o = tid; o < 6400; o += 256) {
        int pp = o / 100; int k = o - 100 * pp;
        if (pp < pcnt) W7fT[(size_t)(p0 + pp) * 100 + k] = tile[k * 65 + pp];
    }
}

// ---------------- K1: attention pools -> cat1[B][200] ----------------
__global__ __launch_bounds__(256) void k1(const float* __restrict__ x, const float* __restrict__ usf,
                                          const float* __restrict__ csf, float* __restrict__ cat1) {
    __shared__ float xs[N_ * 101];
    __shared__ float zs[2][64];
    __shared__ float wsm[2][64];
    __shared__ float uss[200];
    __shared__ float css[2];
    int b = blockIdx.x; int tid = threadIdx.x;
    const float* xr = x + (size_t)b * (N_ * E_);
    for (int li = tid; li < (N_ * E_) / 4; li += 256) {   // 1250 float4s
        float4 vv = ((const float4*)xr)[li];
        int flat = li * 4; int n = flat / 100; int e = flat - n * 100;
        float* d = xs + n * 101 + e;                       // e<=96, stays in row
        d[0] = vv.x; d[1] = vv.y; d[2] = vv.z; d[3] = vv.w;
    }
    if (tid < 200) uss[tid] = usf[tid];
    if (tid < 2) css[tid] = csf[tid];
    __syncthreads();
    if (tid < 100) {
        int h = (tid >= 50); int n = tid - 50 * h;
        float z = css[h];
        const float* u = uss + h * 100;
        for (int e = 0; e < 100; e++) z = fmaf(xs[n * 101 + e], u[e], z);
        zs[h][n] = expf(z);          // logits = exp(h @ W2^T)
    }
    __syncthreads();
    int wv = tid >> 6, ln = tid & 63;
    if (wv < 2) {
        float a = (ln < 50) ? zs[wv][ln] : -3.0e38f;
        float m = a;
        for (int s = 1; s < 64; s <<= 1) m = fmaxf(m, __shfl_xor(m, s, 64));
        float ex = (ln < 50) ? expf(a - m) : 0.f;
        float ss = ex;
        for (int s = 1; s < 64; s <<= 1) ss += __shfl_xor(ss, s, 64);
        if (ln < 50) wsm[wv][ln] = ex / ss;   // softmax over N
    }
    __syncthreads();
    if (tid < 200) {
        int h = (tid >= 100); int e = tid - 100 * h;
        float q = 0.f;
        for (int n = 0; n < 50; n++) q = fmaf(xs[n * 101 + e], wsm[h][n], q);
        cat1[(size_t)b * 200 + tid] = q;      // [q1 | q2]
    }
}

// ---------------- K2: h5, h6, cross-feature x W7 ----------------
// All weight streams (W5fT/W6fT/W7fT) are staged into LDS in double-buffered
// 64-row chunks by coalesced cooperative float4 loads (deep vmcnt pipelining),
// and consumed by ds_read_b128 BROADCAST (all lanes same address: conflict-free).
// Inner loops contain only DS ops + FMA -> fine-grained lgkmcnt, no per-step
// global latency on the critical path (the round-0/round-1 stall).
// k-slices 28 wide at {0,28,56,72}; 72..83 overlap computed identically by two
// waves (benign duplicate writes). LDS: 25.9 + 51.2 + 0.5 = 77.6 KB (2 blocks/CU).
__global__ __launch_bounds__(256, 2) void k2(const float* __restrict__ cat1,
        const float* __restrict__ W5fT, const float* __restrict__ W6fT,
        const float* __restrict__ b5f, const float* __restrict__ b6f,
        const float* __restrict__ W7fT, const int* __restrict__ pairIJ,
        float* __restrict__ h6T, float* __restrict__ h7Tp) {
    __shared__ float sbuf[64 * 101];                 // cat1 half-tile, then h5 tile
    __shared__ __align__(16) float wch[2][64 * 100]; // weight chunk double buffer
    __shared__ int pijc[2][64];
    const int g  = blockIdx.x >> 7;          // pair group 0..3
    const int rb = blockIdx.x & 127;
    const int r0 = rb * 64;
    const int tid = threadIdx.x;
    const int lane = tid & 63;
    const int w = tid >> 6;
    const int kbase = (w < 3) ? w * 28 : 72;
    const int hbase = lane * 101;

    float acc[28];

    // ================= phase A: h5 = cat1 @ W5^T + b5 =================
    {
        const float4* bp = (const float4*)(b5f + kbase);
        #pragma unroll
        for (int q = 0; q < 7; q++) {
            float4 t = bp[q];
            acc[4*q] = t.x; acc[4*q+1] = t.y; acc[4*q+2] = t.z; acc[4*q+3] = t.w;
        }
    }
    for (int half = 0; half < 2; half++) {
        const float* Wg = W5fT + half * 10000;      // rows j = half*100 ..
        if (half) __syncthreads();                  // prior sbuf readers done
        // stage cat1 half-tile -> sbuf (coalesced)
        for (int o = tid; o < 6400; o += 256) {
            int r = o / 100; int j = o - r * 100;
            sbuf[r * 101 + j] = cat1[(size_t)(r0 + r) * 200 + half * 100 + j];
        }
        // stage weight chunk0 (rows 0..63) -> wch[0]
        {
            const float4* src4 = (const float4*)Wg;
            #pragma unroll
            for (int k = 0; k < 7; k++) {
                int o = tid + (k << 8);
                if (o < 1600) ((float4*)wch[0])[o] = src4[o];
            }
        }
        __syncthreads();
        int cur = 0;
        for (int c = 0; c < 2; c++) {
            int rbase = c << 6;
            int rc = (c == 0) ? 64 : 36;
            // issue next-chunk global loads into regs (T14 issue-early)
            float4 stg[7];
            int nf4n = (c == 0) ? 900 : 0;           // 36 rows * 25 f4
            const float4* src4 = (const float4*)(Wg + 6400);
            #pragma unroll
            for (int k = 0; k < 7; k++) {
                int o = tid + (k << 8);
                if (o < nf4n) stg[k] = src4[o];
            }
            // compute rc rows from wch[cur]
            const float* wb = wch[cur];
            for (int r = 0; r < rc; r++) {
                float s = sbuf[hbase + rbase + r];
                const float4* wl = (const float4*)(wb + r * 100 + kbase);
                #pragma unroll
                for (int q = 0; q < 7; q++) {
                    float4 wv = wl[q];
                    acc[4*q]   = fmaf(s, wv.x, acc[4*q]);
                    acc[4*q+1] = fmaf(s, wv.y, acc[4*q+1]);
                    acc[4*q+2] = fmaf(s, wv.z, acc[4*q+2]);
                    acc[4*q+3] = fmaf(s, wv.w, acc[4*q+3]);
                }
            }
            // write-late
            #pragma unroll
            for (int k = 0; k < 7; k++) {
                int o = tid + (k << 8);
                if (o < nf4n) ((float4*)wch[cur ^ 1])[o] = stg[k];
            }
            __syncthreads();
            cur ^= 1;
        }
    }
    // publish h5 tile to sbuf (all readers of cat1-half-1 are past the last barrier)
    #pragma unroll
    for (int m = 0; m < 28; m++) sbuf[hbase + kbase + m] = acc[m];
    __syncthreads();

    // ================= phase B: h6 = h5 @ W6^T + b6 (group 0 only) =================
    if (g == 0) {
        {
            const float4* bp = (const float4*)(b6f + kbase);
            #pragma unroll
            for (int q = 0; q < 7; q++) {
                float4 t = bp[q];
                acc[4*q] = t.x; acc[4*q+1] = t.y; acc[4*q+2] = t.z; acc[4*q+3] = t.w;
            }
        }
        {
            const float4* src4 = (const float4*)W6fT;
            #pragma unroll
            for (int k = 0; k < 7; k++) {
                int o = tid + (k << 8);
                if (o < 1600) ((float4*)wch[0])[o] = src4[o];
            }
        }
        __syncthreads();
        int cur = 0;
        for (int c = 0; c < 2; c++) {
            int rbase = c << 6;
            int rc = (c == 0) ? 64 : 36;
            float4 stg[7];
            int nf4n = (c == 0) ? 900 : 0;
            const float4* src4 = (const float4*)(W6fT + 6400);
            #pragma unroll
            for (int k = 0; k < 7; k++) {
                int o = tid + (k << 8);
                if (o < nf4n) stg[k] = src4[o];
            }
            const float* wb = wch[cur];
            for (int r = 0; r < rc; r++) {
                float s = sbuf[hbase + rbase + r];
                const float4* wl = (const float4*)(wb + r * 100 + kbase);
                #pragma unroll
                for (int q = 0; q < 7; q++) {
                    float4 wv = wl[q];
                    acc[4*q]   = fmaf(s, wv.x, acc[4*q]);
                    acc[4*q+1] = fmaf(s, wv.y, acc[4*q+1]);
                    acc[4*q+2] = fmaf(s, wv.z, acc[4*q+2]);
                    acc[4*q+3] = fmaf(s, wv.w, acc[4*q+3]);
                }
            }
            #pragma unroll
            for (int k = 0; k < 7; k++) {
                int o = tid + (k << 8);
                if (o < nf4n) ((float4*)wch[cur ^ 1])[o] = stg[k];
            }
            __syncthreads();
            cur ^= 1;
        }
        #pragma unroll
        for (int m = 0; m < 28; m++) h6T[(size_t)(kbase + m) * B_ + r0 + lane] = acc[m];
    }

    // ================= phase C: h7 partial over this group's pairs =================
    #pragma unroll
    for (int m = 0; m < 28; m++) acc[m] = 0.f;
    const int pstart = g * 1238;
    const int np = min(NPAIR - pstart, 1238);
    const float* Wg = W7fT + (size_t)pstart * 100;
    const int NCH = (np + 63) >> 6;                  // 20
    {
        int rc0 = min(64, np);
        int nf4 = rc0 * 25;
        const float4* src4 = (const float4*)Wg;
        #pragma unroll
        for (int k = 0; k < 7; k++) {
            int o = tid + (k << 8);
            if (o < nf4) ((float4*)wch[0])[o] = src4[o];
        }
        if (tid < rc0) pijc[0][tid] = pairIJ[pstart + tid];
    }
    __syncthreads();
    int cur = 0;
    for (int c = 0; c < NCH; c++) {
        int rbase = c << 6;
        int rc = min(64, np - rbase);
        // issue next-chunk loads
        float4 stg[7];
        int pv = 0;
        int rcn = (c + 1 < NCH) ? min(64, np - rbase - 64) : 0;
        int nf4n = rcn * 25;
        const float4* src4 = (const float4*)(Wg + (size_t)(rbase + 64) * 100);
        #pragma unroll
        for (int k = 0; k < 7; k++) {
            int o = tid + (k << 8);
            if (o < nf4n) stg[k] = src4[o];
        }
        if (tid < rcn) pv = pairIJ[pstart + rbase + 64 + tid];
        // compute rc pairs from wch[cur], cf prefetched one ahead
        const float* wb = wch[cur];
        int ij0 = pijc[cur][0];
        float cf = sbuf[hbase + (ij0 >> 8)] * sbuf[hbase + (ij0 & 255)];
        for (int r = 0; r < rc; r++) {
            float cfn = 0.f;
            if (r + 1 < rc) {
                int ij = pijc[cur][r + 1];
                cfn = sbuf[hbase + (ij >> 8)] * sbuf[hbase + (ij & 255)];
            }
            const float4* wl = (const float4*)(wb + r * 100 + kbase);
            #pragma unroll
            for (int q = 0; q < 7; q++) {
                float4 wv = wl[q];
                acc[4*q]   = fmaf(cf, wv.x, acc[4*q]);
                acc[4*q+1] = fmaf(cf, wv.y, acc[4*q+1]);
                acc[4*q+2] = fmaf(cf, wv.z, acc[4*q+2]);
                acc[4*q+3] = fmaf(cf, wv.w, acc[4*q+3]);
            }
            cf = cfn;
        }
        // write-late
        #pragma unroll
        for (int k = 0; k < 7; k++) {
            int o = tid + (k << 8);
            if (o < nf4n) ((float4*)wch[cur ^ 1])[o] = stg[k];
        }
        if (tid < rcn) pijc[cur ^ 1][tid] = pv;
        __syncthreads();
        cur ^= 1;
    }
    float* h7p = h7Tp + (size_t)g * 100 * B_;
    #pragma unroll
    for (int m = 0; m < 28; m++)
        h7p[(size_t)(kbase + m) * B_ + r0 + lane] = acc[m];
}

// ---------------- K3a: h8T = W8 @ [h6; sum(h7 partials)] + c8 ----------------
// 8 waves: (w&3) -> 28-wide u-slice {0,28,56,72}; (w>>2) -> e-half (0..99 / 100..199).
// b7 contribution is the precomputed c8f. Halves combined through LDS.
__global__ __launch_bounds__(512, 2) void k3a(const float* __restrict__ h6T, const float* __restrict__ h7Tp,
        const float* __restrict__ c8f, const float* __restrict__ W8fT, float* __restrict__ h8T) {
    __shared__ float part[100 * 64];
    int tid = threadIdx.x;
    int lane = tid & 63;
    int w = tid >> 6;
    int ws_ = w & 3;
    int half = w >> 2;
    int ubase = (ws_ < 3) ? ws_ * 28 : 72;
    int b = blockIdx.x * 64 + lane;
    float acc[28];
    if (half) {
        const float4* cp = (const float4*)(c8f + ubase);
        #pragma unroll
        for (int q = 0; q < 7; q++) {
            float4 t = cp[q];
            acc[4*q] = t.x; acc[4*q+1] = t.y; acc[4*q+2] = t.z; acc[4*q+3] = t.w;
        }
    } else {
        #pragma unroll
        for (int m = 0; m < 28; m++) acc[m] = 0.f;
    }
    const float* wb = W8fT + (half ? 10000 : 0) + ubase;
    #pragma unroll 2
    for (int e = 0; e < 100; e++) {
        float vv;
        if (half) {
            vv = h7Tp[(size_t)e * B_ + b]
               + h7Tp[(size_t)(100 + e) * B_ + b]
               + h7Tp[(size_t)(200 + e) * B_ + b]
               + h7Tp[(size_t)(300 + e) * B_ + b];
        } else {
            vv = h6T[(size_t)e * B_ + b];
        }
        const float4* wp = (const float4*)(wb + e * 100);
        #pragma unroll
        for (int q = 0; q < 7; q++) {
            float4 wv = wp[q];
            acc[4*q]   = fmaf(vv, wv.x, acc[4*q]);
            acc[4*q+1] = fmaf(vv, wv.y, acc[4*q+1]);
            acc[4*q+2] = fmaf(vv, wv.z, acc[4*q+2]);
            acc[4*q+3] = fmaf(vv, wv.w, acc[4*q+3]);
        }
    }
    if (half) {
        #pragma unroll
        for (int m = 0; m < 28; m++) part[(ubase + m) * 64 + lane] = acc[m];
    }
    __syncthreads();
    if (!half) {
        #pragma unroll
        for (int m = 0; m < 28; m++)
            h8T[(size_t)(ubase + m) * B_ + b] = acc[m] + part[(ubase + m) * 64 + lane];
    }
}

// ---------------- K3b: out = h8 @ label_embedding (+ b8@le folded bias) ----------------
__global__ __launch_bounds__(256) void k3b(const float* __restrict__ h8T, const float* __restrict__ le,
        const float* __restrict__ bl8f, float* __restrict__ out) {
    int lq = blockIdx.x & 3; int bb = blockIdx.x >> 2;
    int b0 = bb * 32;
    int l = lq * 256 + threadIdx.x;
    bool valid = (l < L_);
    int lc = valid ? l : 0;
    unsigned off0 = 0;
    asm volatile("" : "+v"(off0));           // opaque zero in a VGPR: defeat uniform-addr scalarization
    const float* hb = h8T + b0 + off0;
    float acc[32];
    #pragma unroll
    for (int i = 0; i < 32; i++) acc[i] = 0.f;
    #pragma unroll 2
    for (int u = 0; u < 100; u++) {
        float lev = le[u * 1000 + lc];
        const float4* hp = (const float4*)(hb + (size_t)u * B_);
        #pragma unroll
        for (int q = 0; q < 8; q++) {
            float4 hv = hp[q];
            acc[4*q]   = fmaf(hv.x, lev, acc[4*q]);
            acc[4*q+1] = fmaf(hv.y, lev, acc[4*q+1]);
            acc[4*q+2] = fmaf(hv.z, lev, acc[4*q+2]);
            acc[4*q+3] = fmaf(hv.w, lev, acc[4*q+3]);
        }
    }
    if (valid) {
        float bias = bl8f[l];
        #pragma unroll
        for (int i = 0; i < 32; i++)
            out[(size_t)(b0 + i) * 1000 + l] = acc[i] + bias;
    }
}

extern "C" void kernel_launch(void* const* d_in, const int* in_sizes, int n_in,
                              void* d_out, int out_size, void* d_ws, size_t ws_size,
                              hipStream_t stream) {
    const float* x  = (const float*)d_in[0];
    const float* v  = (const float*)d_in[1];
    const float* W1 = (const float*)d_in[2];
    const float* b1 = (const float*)d_in[3];
    const float* W2 = (const float*)d_in[4];
    const float* W3 = (const float*)d_in[5];
    const float* b3 = (const float*)d_in[6];
    const float* W4 = (const float*)d_in[7];
    const float* W5 = (const float*)d_in[8];
    const float* b5 = (const float*)d_in[9];
    const float* W6 = (const float*)d_in[10];
    const float* b6 = (const float*)d_in[11];
    const float* W7 = (const float*)d_in[12];
    const float* b7 = (const float*)d_in[13];
    const float* W8 = (const float*)d_in[14];
    const float* b8 = (const float*)d_in[15];
    const float* le = (const float*)d_in[16];
    float* out = (float*)d_out;
    float* ws = (float*)d_ws;

    float* cat1   = ws;                 // 1,638,400
    float* h6T    = ws + 1638400;       //   819,200
    float* h7Tp   = ws + 2457600;       // 3,276,800 (4 partials x 100 x B)
    float* h8T    = ws + 5734400;       //   819,200
    float* W7fT   = ws + 6553600;       //   495,000
    float* W5fT   = ws + 7048600;       //    20,000
    float* W6fT   = ws + 7068600;       //    10,000
    float* W8fT   = ws + 7078600;       //    20,000
    float* usf    = ws + 7098600;       //       200
    float* csf    = ws + 7098800;       //       2 (+2 pad)
    float* b5f    = ws + 7098804;       //       100
    float* b6f    = ws + 7098904;       //       100
    float* b7f    = ws + 7099004;       //       100
    float* bl8f   = ws + 7099104;       //      1000
    float* vvp    = ws + 7100104;       //      4950
    int*   pairIJ = (int*)(ws + 7105054); //    4950
    float* c8f    = ws + 7110004;       //       100

    k0a<<<1, 256, 0, stream>>>(v, W1, b1, W2, W3, b3, W4, b5, b6, b7,
                               usf, csf, b5f, b6f, b7f, vvp, pairIJ);
    k0b<<<196, 256, 0, stream>>>(W5, W6, W8, W5fT, W6fT, W8fT);
    k0c<<<5, 256, 0, stream>>>(b8, le, b7, W8, bl8f, c8f);
    k0d<<<78, 256, 0, stream>>>(W7, vvp, W7fT);
    k1<<<8192, 256, 0, stream>>>(x, usf, csf, cat1);
    k2<<<512, 256, 0, stream>>>(cat1, W5fT, W6fT, b5f, b6f, W7fT, pairIJ, h6T, h7Tp);
    k3a<<<128, 512, 0, stream>>>(h6T, h7Tp, c8f, W8fT, h8T);
    k3b<<<1024, 256, 0, stream>>>(h8T, le, bl8f, out);
}

// Round 3
// 696.400 us; speedup vs baseline: 1.5125x; 1.1324x over previous
//
#include <hip/hip_runtime.h>
#include <cstdint>
#include <cstddef>

#define E_    100
#define N_    50
#define B_    8192
#define L_    1000
#define NPAIR 4950

// ---------------- K0a: tiny precomputes (attention u/c vectors, bias copies, pair table, vv) ----
__global__ __launch_bounds__(256) void k0a(const float* __restrict__ v,
        const float* __restrict__ W1, const float* __restrict__ b1, const float* __restrict__ W2,
        const float* __restrict__ W3, const float* __restrict__ b3, const float* __restrict__ W4,
        const float* __restrict__ b5, const float* __restrict__ b6, const float* __restrict__ b7,
        float* __restrict__ usf, float* __restrict__ csf,
        float* __restrict__ b5f, float* __restrict__ b6f, float* __restrict__ b7f,
        float* __restrict__ vvp, int* __restrict__ pairIJ) {
    int tid = threadIdx.x;
    if (tid < 200) {
        int h = (tid >= 100); int e = tid - 100 * h;
        const float* Wa = h ? W3 : W1; const float* Wb = h ? W4 : W2;
        float u = 0.f;
        for (int t = 0; t < 8; t++) u += Wa[t * 100 + e] * Wb[t];
        usf[tid] = u;
    } else if (tid < 202) {
        int h = tid - 200;
        const float* bb = h ? b3 : b1; const float* Wb = h ? W4 : W2;
        float c = 0.f;
        for (int t = 0; t < 8; t++) c += bb[t] * Wb[t];
        csf[h] = c;
    }
    if (tid < 100) {
        b5f[tid] = b5[tid];
        b6f[tid] = b6[tid];
        b7f[tid] = b7[tid];
        int i = tid;
        int base = i * 99 - (i * (i - 1)) / 2;  // start of triu row i (k=1), i-major
        float vi0 = v[i * 4 + 0], vi1 = v[i * 4 + 1];
        float vi2 = v[i * 4 + 2], vi3 = v[i * 4 + 3];
        for (int j = i + 1; j < 100; j++) {
            int p = base + (j - i - 1);
            pairIJ[p] = (i << 8) | j;
            vvp[p] = vi0 * v[j * 4 + 0] + vi1 * v[j * 4 + 1]
                   + vi2 * v[j * 4 + 2] + vi3 * v[j * 4 + 3];
        }
    }
}

// ---------------- K0b: transpose W5,W6,W8 ----------------
__global__ __launch_bounds__(256) void k0b(const float* __restrict__ W5, const float* __restrict__ W6,
        const float* __restrict__ W8, float* __restrict__ W5fT, float* __restrict__ W6fT,
        float* __restrict__ W8fT) {
    int gid = blockIdx.x * 256 + threadIdx.x;
    if (gid < 20000) {                       // W5fT[j][t] = W5[t][j], j<200,t<100
        int o = gid; int j = o / 100; int t = o - 100 * j;
        W5fT[o] = W5[t * 200 + j];
    } else if (gid < 30000) {                // W6fT[j][t] = W6[t][j]
        int o = gid - 20000; int j = o / 100; int t = o - 100 * j;
        W6fT[o] = W6[t * 100 + j];
    } else if (gid < 50000) {                // W8fT[e][u] = W8[u][e], e<200,u<100
        int o = gid - 30000; int e = o / 100; int u = o - 100 * e;
        W8fT[o] = W8[u * 200 + e];
    }
}

// ---------------- K0c: bl8f[l] = sum_u b8[u]*le[u][l];  c8f[u] = sum_t b7[t]*W8[u][100+t] ----
__global__ __launch_bounds__(256) void k0c(const float* __restrict__ b8, const float* __restrict__ le,
                                           const float* __restrict__ b7, const float* __restrict__ W8,
                                           float* __restrict__ bl8f, float* __restrict__ c8f) {
    int gid = blockIdx.x * 256 + threadIdx.x;
    if (gid < L_) {
        float acc = 0.f;
        for (int u = 0; u < 100; u++) acc += b8[u] * le[u * 1000 + gid];
        bl8f[gid] = acc;
    } else if (gid < L_ + 100) {
        int u = gid - L_;
        float acc = 0.f;
        for (int t = 0; t < 100; t++) acc += b7[t] * W8[u * 200 + 100 + t];
        c8f[u] = acc;
    }
}

// ---------------- K0d: W7fT[p][k] = W7[k][p] * vvp[p] (transposed, vv folded) ----------------
__global__ __launch_bounds__(256) void k0d(const float* __restrict__ W7, const float* __restrict__ vvp,
                                           float* __restrict__ W7fT) {
    __shared__ float tile[100 * 65];
    __shared__ float vvs[64];
    int p0 = blockIdx.x * 64;
    int tid = threadIdx.x; int pl = tid & 63;
    int pcnt = min(64, NPAIR - p0);
    if (tid < 64) vvs[tid] = (p0 + tid < NPAIR) ? vvp[p0 + tid] : 0.f;
    __syncthreads();
    for (int kk = tid >> 6; kk < 100; kk += 4) {
        float w = (pl < pcnt) ? W7[kk * NPAIR + p0 + pl] : 0.f;
        tile[kk * 65 + pl] = w * vvs[pl];
    }
    __syncthreads();
    for (int o = tid; o < 6400; o += 256) {
        int pp = o / 100; int k = o - 100 * pp;
        if (pp < pcnt) W7fT[(size_t)(p0 + pp) * 100 + k] = tile[k * 65 + pp];
    }
}

// ---------------- K1: attention pools -> cat1[B][200] ----------------
__global__ __launch_bounds__(256) void k1(const float* __restrict__ x, const float* __restrict__ usf,
                                          const float* __restrict__ csf, float* __restrict__ cat1) {
    __shared__ float xs[N_ * 101];
    __shared__ float zs[2][64];
    __shared__ float wsm[2][64];
    __shared__ float uss[200];
    __shared__ float css[2];
    int b = blockIdx.x; int tid = threadIdx.x;
    const float* xr = x + (size_t)b * (N_ * E_);
    for (int li = tid; li < (N_ * E_) / 4; li += 256) {   // 1250 float4s
        float4 vv = ((const float4*)xr)[li];
        int flat = li * 4; int n = flat / 100; int e = flat - n * 100;
        float* d = xs + n * 101 + e;                       // e<=96, stays in row
        d[0] = vv.x; d[1] = vv.y; d[2] = vv.z; d[3] = vv.w;
    }
    if (tid < 200) uss[tid] = usf[tid];
    if (tid < 2) css[tid] = csf[tid];
    __syncthreads();
    if (tid < 100) {
        int h = (tid >= 50); int n = tid - 50 * h;
        float z = css[h];
        const float* u = uss + h * 100;
        for (int e = 0; e < 100; e++) z = fmaf(xs[n * 101 + e], u[e], z);
        zs[h][n] = expf(z);          // logits = exp(h @ W2^T)
    }
    __syncthreads();
    int wv = tid >> 6, ln = tid & 63;
    if (wv < 2) {
        float a = (ln < 50) ? zs[wv][ln] : -3.0e38f;
        float m = a;
        for (int s = 1; s < 64; s <<= 1) m = fmaxf(m, __shfl_xor(m, s, 64));
        float ex = (ln < 50) ? expf(a - m) : 0.f;
        float ss = ex;
        for (int s = 1; s < 64; s <<= 1) ss += __shfl_xor(ss, s, 64);
        if (ln < 50) wsm[wv][ln] = ex / ss;   // softmax over N
    }
    __syncthreads();
    if (tid < 200) {
        int h = (tid >= 100); int e = tid - 100 * h;
        float q = 0.f;
        for (int n = 0; n < 50; n++) q = fmaf(xs[n * 101 + e], wsm[h][n], q);
        cat1[(size_t)b * 200 + tid] = q;      // [q1 | q2]
    }
}

// ---------------- K2: h5, h6, cross-feature x W7 ----------------
// 8-wave (512-thread) blocks on the same 512-block grid -> 2 blocks/CU x 8 waves
// = 4 waves/SIMD (was 2): doubles latency-hiding for the LDS->FMA chains and
// barrier drains that caused the 70% stall at 2 waves/SIMD.
// Wave split: grp = w>>2 (row parity within each chunk), wk = w&3 (k-slice).
// Each group keeps its own accumulator; combined once per phase through wch[0].
// Weights staged in LDS double-buffered 64-row chunks (broadcast ds_read_b128).
__global__ __launch_bounds__(512, 4) void k2(const float* __restrict__ cat1,
        const float* __restrict__ W5fT, const float* __restrict__ W6fT,
        const float* __restrict__ b5f, const float* __restrict__ b6f,
        const float* __restrict__ W7fT, const int* __restrict__ pairIJ,
        float* __restrict__ h6T, float* __restrict__ h7Tp) {
    __shared__ float sbuf[64 * 101];                 // cat1 half-tile, then h5 tile
    __shared__ __align__(16) float wch[2][64 * 100]; // weight chunk double buffer / combine buf
    __shared__ int pijc[2][64];
    const int g  = blockIdx.x >> 7;          // pair group 0..3
    const int rb = blockIdx.x & 127;
    const int r0 = rb * 64;
    const int tid = threadIdx.x;
    const int lane = tid & 63;
    const int w = tid >> 6;
    const int grp = w >> 2;                  // 0: even rows, 1: odd rows
    const int wk = w & 3;
    const int kbase = (wk < 3) ? wk * 28 : 72;
    const int hbase = lane * 101;
    float* comb = wch[0];

    float acc[28];

    // ================= phase A: h5 = cat1 @ W5^T + b5 =================
    if (!grp) {
        const float4* bp = (const float4*)(b5f + kbase);
        #pragma unroll
        for (int q = 0; q < 7; q++) {
            float4 t = bp[q];
            acc[4*q] = t.x; acc[4*q+1] = t.y; acc[4*q+2] = t.z; acc[4*q+3] = t.w;
        }
    } else {
        #pragma unroll
        for (int m = 0; m < 28; m++) acc[m] = 0.f;
    }
    for (int half = 0; half < 2; half++) {
        const float* Wg = W5fT + half * 10000;      // rows j = half*100 ..
        // stage cat1 half-tile -> sbuf (coalesced); prior readers done (loop ends in barrier)
        for (int o = tid; o < 6400; o += 512) {
            int r = o / 100; int j = o - r * 100;
            sbuf[r * 101 + j] = cat1[(size_t)(r0 + r) * 200 + half * 100 + j];
        }
        // stage weight chunk0 (rows 0..63) -> wch[0]
        {
            const float4* src4 = (const float4*)Wg;
            #pragma unroll
            for (int k = 0; k < 4; k++) {
                int o = tid + (k << 9);
                if (o < 1600) ((float4*)wch[0])[o] = src4[o];
            }
        }
        __syncthreads();
        int cur = 0;
        for (int c = 0; c < 2; c++) {
            int rbase = c << 6;
            int rc = (c == 0) ? 64 : 36;
            // issue next-chunk global loads into regs (T14 issue-early)
            float4 stg[4];
            int nf4n = (c == 0) ? 900 : 0;           // 36 rows * 25 f4
            const float4* src4 = (const float4*)(Wg + 6400);
            #pragma unroll
            for (int k = 0; k < 4; k++) {
                int o = tid + (k << 9);
                if (o < nf4n) stg[k] = src4[o];
            }
            // compute this group's parity rows from wch[cur]
            const float* wb = wch[cur];
            for (int r = grp; r < rc; r += 2) {
                float s = sbuf[hbase + rbase + r];
                const float4* wl = (const float4*)(wb + r * 100 + kbase);
                #pragma unroll
                for (int q = 0; q < 7; q++) {
                    float4 wv = wl[q];
                    acc[4*q]   = fmaf(s, wv.x, acc[4*q]);
                    acc[4*q+1] = fmaf(s, wv.y, acc[4*q+1]);
                    acc[4*q+2] = fmaf(s, wv.z, acc[4*q+2]);
                    acc[4*q+3] = fmaf(s, wv.w, acc[4*q+3]);
                }
            }
            // write-late
            #pragma unroll
            for (int k = 0; k < 4; k++) {
                int o = tid + (k << 9);
                if (o < nf4n) ((float4*)wch[cur ^ 1])[o] = stg[k];
            }
            __syncthreads();
            cur ^= 1;
        }
    }
    // combine grpB partial into grpA, publish h5 to sbuf
    if (grp) {
        #pragma unroll
        for (int m = 0; m < 28; m++) comb[lane * 100 + kbase + m] = acc[m];
    }
    __syncthreads();
    if (!grp) {
        #pragma unroll
        for (int m = 0; m < 28; m++) acc[m] += comb[lane * 100 + kbase + m];
        #pragma unroll
        for (int m = 0; m < 28; m++) sbuf[hbase + kbase + m] = acc[m];
    }
    __syncthreads();   // h5 visible; comb free for reuse

    // ================= phase B: h6 = h5 @ W6^T + b6 (group 0 only) =================
    if (g == 0) {
        if (!grp) {
            const float4* bp = (const float4*)(b6f + kbase);
            #pragma unroll
            for (int q = 0; q < 7; q++) {
                float4 t = bp[q];
                acc[4*q] = t.x; acc[4*q+1] = t.y; acc[4*q+2] = t.z; acc[4*q+3] = t.w;
            }
        } else {
            #pragma unroll
            for (int m = 0; m < 28; m++) acc[m] = 0.f;
        }
        {
            const float4* src4 = (const float4*)W6fT;
            #pragma unroll
            for (int k = 0; k < 4; k++) {
                int o = tid + (k << 9);
                if (o < 1600) ((float4*)wch[0])[o] = src4[o];
            }
        }
        __syncthreads();
        int cur = 0;
        for (int c = 0; c < 2; c++) {
            int rbase = c << 6;
            int rc = (c == 0) ? 64 : 36;
            float4 stg[4];
            int nf4n = (c == 0) ? 900 : 0;
            const float4* src4 = (const float4*)(W6fT + 6400);
            #pragma unroll
            for (int k = 0; k < 4; k++) {
                int o = tid + (k << 9);
                if (o < nf4n) stg[k] = src4[o];
            }
            const float* wb = wch[cur];
            for (int r = grp; r < rc; r += 2) {
                float s = sbuf[hbase + rbase + r];
                const float4* wl = (const float4*)(wb + r * 100 + kbase);
                #pragma unroll
                for (int q = 0; q < 7; q++) {
                    float4 wv = wl[q];
                    acc[4*q]   = fmaf(s, wv.x, acc[4*q]);
                    acc[4*q+1] = fmaf(s, wv.y, acc[4*q+1]);
                    acc[4*q+2] = fmaf(s, wv.z, acc[4*q+2]);
                    acc[4*q+3] = fmaf(s, wv.w, acc[4*q+3]);
                }
            }
            #pragma unroll
            for (int k = 0; k < 4; k++) {
                int o = tid + (k << 9);
                if (o < nf4n) ((float4*)wch[cur ^ 1])[o] = stg[k];
            }
            __syncthreads();
            cur ^= 1;
        }
        if (grp) {
            #pragma unroll
            for (int m = 0; m < 28; m++) comb[lane * 100 + kbase + m] = acc[m];
        }
        __syncthreads();
        if (!grp) {
            #pragma unroll
            for (int m = 0; m < 28; m++) acc[m] += comb[lane * 100 + kbase + m];
            #pragma unroll
            for (int m = 0; m < 28; m++) h6T[(size_t)(kbase + m) * B_ + r0 + lane] = acc[m];
        }
        __syncthreads();   // comb free before phase C staging
    }

    // ================= phase C: h7 partial over this group's pairs =================
    #pragma unroll
    for (int m = 0; m < 28; m++) acc[m] = 0.f;
    const int pstart = g * 1238;
    const int np = min(NPAIR - pstart, 1238);
    const float* Wg = W7fT + (size_t)pstart * 100;
    const int NCH = (np + 63) >> 6;                  // 20
    {
        int rc0 = min(64, np);
        int nf4 = rc0 * 25;
        const float4* src4 = (const float4*)Wg;
        #pragma unroll
        for (int k = 0; k < 4; k++) {
            int o = tid + (k << 9);
            if (o < nf4) ((float4*)wch[0])[o] = src4[o];
        }
        if (tid < rc0) pijc[0][tid] = pairIJ[pstart + tid];
    }
    __syncthreads();
    int cur = 0;
    for (int c = 0; c < NCH; c++) {
        int rbase = c << 6;
        int rc = min(64, np - rbase);
        // issue next-chunk loads
        float4 stg[4];
        int pv = 0;
        int rcn = (c + 1 < NCH) ? min(64, np - rbase - 64) : 0;
        int nf4n = rcn * 25;
        const float4* src4 = (const float4*)(Wg + (size_t)(rbase + 64) * 100);
        #pragma unroll
        for (int k = 0; k < 4; k++) {
            int o = tid + (k << 9);
            if (o < nf4n) stg[k] = src4[o];
        }
        if (tid < rcn) pv = pairIJ[pstart + rbase + 64 + tid];
        // compute this group's parity pairs from wch[cur]
        const float* wb = wch[cur];
        for (int r = grp; r < rc; r += 2) {
            int ij = pijc[cur][r];
            float cf = sbuf[hbase + (ij >> 8)] * sbuf[hbase + (ij & 255)];
            const float4* wl = (const float4*)(wb + r * 100 + kbase);
            #pragma unroll
            for (int q = 0; q < 7; q++) {
                float4 wv = wl[q];
                acc[4*q]   = fmaf(cf, wv.x, acc[4*q]);
                acc[4*q+1] = fmaf(cf, wv.y, acc[4*q+1]);
                acc[4*q+2] = fmaf(cf, wv.z, acc[4*q+2]);
                acc[4*q+3] = fmaf(cf, wv.w, acc[4*q+3]);
            }
        }
        // write-late
        #pragma unroll
        for (int k = 0; k < 4; k++) {
            int o = tid + (k << 9);
            if (o < nf4n) ((float4*)wch[cur ^ 1])[o] = stg[k];
        }
        if (tid < rcn) pijc[cur ^ 1][tid] = pv;
        __syncthreads();
        cur ^= 1;
    }
    if (grp) {
        #pragma unroll
        for (int m = 0; m < 28; m++) comb[lane * 100 + kbase + m] = acc[m];
    }
    __syncthreads();
    if (!grp) {
        #pragma unroll
        for (int m = 0; m < 28; m++) acc[m] += comb[lane * 100 + kbase + m];
        float* h7p = h7Tp + (size_t)g * 100 * B_;
        #pragma unroll
        for (int m = 0; m < 28; m++)
            h7p[(size_t)(kbase + m) * B_ + r0 + lane] = acc[m];
    }
}

// ---------------- K3a: h8T = W8 @ [h6; sum(h7 partials)] + c8 ----------------
// Regridded 128x512 -> 512x256: all 256 CUs active (was half idle), 2 waves/SIMD.
// 16-batch tiles; wave w owns e-range [50w,50w+50) (wave-uniform h6/h7 branch);
// lane>>4 owns a 28-wide u-slice {0,28,56,72} (72..83 dup, identical values).
// Waves 1-3 deposit partials in LDS; wave 0 combines, adds c8f, writes.
__global__ __launch_bounds__(256, 2) void k3a(const float* __restrict__ h6T, const float* __restrict__ h7Tp,
        const float* __restrict__ c8f, const float* __restrict__ W8fT, float* __restrict__ h8T) {
    __shared__ float part[3 * 16 * 101];
    int tid = threadIdx.x;
    int lane = tid & 63;
    int w = tid >> 6;
    int bl = lane & 15;
    int ug = lane >> 4;
    int ubase = (ug < 3) ? ug * 28 : 72;
    int b = blockIdx.x * 16 + bl;
    int e0 = w * 50;
    float acc[28];
    #pragma unroll
    for (int m = 0; m < 28; m++) acc[m] = 0.f;
    #pragma unroll 2
    for (int ei = 0; ei < 50; ei++) {
        int e = e0 + ei;
        float vv;
        if (w >= 2) {
            int ee = e - 100;
            vv = h7Tp[(size_t)ee * B_ + b]
               + h7Tp[(size_t)(100 + ee) * B_ + b]
               + h7Tp[(size_t)(200 + ee) * B_ + b]
               + h7Tp[(size_t)(300 + ee) * B_ + b];
        } else {
            vv = h6T[(size_t)e * B_ + b];
        }
        const float4* wp = (const float4*)(W8fT + e * 100 + ubase);
        #pragma unroll
        for (int q = 0; q < 7; q++) {
            float4 wv = wp[q];
            acc[4*q]   = fmaf(vv, wv.x, acc[4*q]);
            acc[4*q+1] = fmaf(vv, wv.y, acc[4*q+1]);
            acc[4*q+2] = fmaf(vv, wv.z, acc[4*q+2]);
            acc[4*q+3] = fmaf(vv, wv.w, acc[4*q+3]);
        }
    }
    if (w >= 1) {
        float* pp = part + (w - 1) * (16 * 101) + bl * 101;
        #pragma unroll
        for (int m = 0; m < 28; m++) pp[ubase + m] = acc[m];
    }
    __syncthreads();
    if (w == 0) {
        const float* p0 = part + bl * 101;
        const float* p1 = part + 16 * 101 + bl * 101;
        const float* p2 = part + 2 * 16 * 101 + bl * 101;
        #pragma unroll
        for (int m = 0; m < 28; m++) {
            float r = acc[m] + p0[ubase + m] + p1[ubase + m] + p2[ubase + m]
                    + c8f[ubase + m];
            h8T[(size_t)(ubase + m) * B_ + b] = r;
        }
    }
}

// ---------------- K3b: out = h8 @ label_embedding (+ b8@le folded bias) ----------------
__global__ __launch_bounds__(256) void k3b(const float* __restrict__ h8T, const float* __restrict__ le,
        const float* __restrict__ bl8f, float* __restrict__ out) {
    int lq = blockIdx.x & 3; int bb = blockIdx.x >> 2;
    int b0 = bb * 32;
    int l = lq * 256 + threadIdx.x;
    bool valid = (l < L_);
    int lc = valid ? l : 0;
    unsigned off0 = 0;
    asm volatile("" : "+v"(off0));           // opaque zero in a VGPR: defeat uniform-addr scalarization
    const float* hb = h8T + b0 + off0;
    float acc[32];
    #pragma unroll
    for (int i = 0; i < 32; i++) acc[i] = 0.f;
    #pragma unroll 2
    for (int u = 0; u < 100; u++) {
        float lev = le[u * 1000 + lc];
        const float4* hp = (const float4*)(hb + (size_t)u * B_);
        #pragma unroll
        for (int q = 0; q < 8; q++) {
            float4 hv = hp[q];
            acc[4*q]   = fmaf(hv.x, lev, acc[4*q]);
            acc[4*q+1] = fmaf(hv.y, lev, acc[4*q+1]);
            acc[4*q+2] = fmaf(hv.z, lev, acc[4*q+2]);
            acc[4*q+3] = fmaf(hv.w, lev, acc[4*q+3]);
        }
    }
    if (valid) {
        float bias = bl8f[l];
        #pragma unroll
        for (int i = 0; i < 32; i++)
            out[(size_t)(b0 + i) * 1000 + l] = acc[i] + bias;
    }
}

extern "C" void kernel_launch(void* const* d_in, const int* in_sizes, int n_in,
                              void* d_out, int out_size, void* d_ws, size_t ws_size,
                              hipStream_t stream) {
    const float* x  = (const float*)d_in[0];
    const float* v  = (const float*)d_in[1];
    const float* W1 = (const float*)d_in[2];
    const float* b1 = (const float*)d_in[3];
    const float* W2 = (const float*)d_in[4];
    const float* W3 = (const float*)d_in[5];
    const float* b3 = (const float*)d_in[6];
    const float* W4 = (const float*)d_in[7];
    const float* W5 = (const float*)d_in[8];
    const float* b5 = (const float*)d_in[9];
    const float* W6 = (const float*)d_in[10];
    const float* b6 = (const float*)d_in[11];
    const float* W7 = (const float*)d_in[12];
    const float* b7 = (const float*)d_in[13];
    const float* W8 = (const float*)d_in[14];
    const float* b8 = (const float*)d_in[15];
    const float* le = (const float*)d_in[16];
    float* out = (float*)d_out;
    float* ws = (float*)d_ws;

    float* cat1   = ws;                 // 1,638,400
    float* h6T    = ws + 1638400;       //   819,200
    float* h7Tp   = ws + 2457600;       // 3,276,800 (4 partials x 100 x B)
    float* h8T    = ws + 5734400;       //   819,200
    float* W7fT   = ws + 6553600;       //   495,000
    float* W5fT   = ws + 7048600;       //    20,000
    float* W6fT   = ws + 7068600;       //    10,000
    float* W8fT   = ws + 7078600;       //    20,000
    float* usf    = ws + 7098600;       //       200
    float* csf    = ws + 7098800;       //       2 (+2 pad)
    float* b5f    = ws + 7098804;       //       100
    float* b6f    = ws + 7098904;       //       100
    float* b7f    = ws + 7099004;       //       100
    float* bl8f   = ws + 7099104;       //      1000
    float* vvp    = ws + 7100104;       //      4950
    int*   pairIJ = (int*)(ws + 7105054); //    4950
    float* c8f    = ws + 7110004;       //       100

    k0a<<<1, 256, 0, stream>>>(v, W1, b1, W2, W3, b3, W4, b5, b6, b7,
                               usf, csf, b5f, b6f, b7f, vvp, pairIJ);
    k0b<<<196, 256, 0, stream>>>(W5, W6, W8, W5fT, W6fT, W8fT);
    k0c<<<5, 256, 0, stream>>>(b8, le, b7, W8, bl8f, c8f);
    k0d<<<78, 256, 0, stream>>>(W7, vvp, W7fT);
    k1<<<8192, 256, 0, stream>>>(x, usf, csf, cat1);
    k2<<<512, 512, 0, stream>>>(cat1, W5fT, W6fT, b5f, b6f, W7fT, pairIJ, h6T, h7Tp);
    k3a<<<512, 256, 0, stream>>>(h6T, h7Tp, c8f, W8fT, h8T);
    k3b<<<1024, 256, 0, stream>>>(h8T, le, bl8f, out);
}

// Round 4
// 638.736 us; speedup vs baseline: 1.6491x; 1.0903x over previous
//
#include <hip/hip_runtime.h>
#include <cstdint>
#include <cstddef>

#define E_    100
#define N_    50
#define B_    8192
#define L_    1000
#define NPAIR 4950

// ---------------- K0a: tiny precomputes (attention u/c vectors, bias copies, pair table, vv) ----
__global__ __launch_bounds__(256) void k0a(const float* __restrict__ v,
        const float* __restrict__ W1, const float* __restrict__ b1, const float* __restrict__ W2,
        const float* __restrict__ W3, const float* __restrict__ b3, const float* __restrict__ W4,
        const float* __restrict__ b5, const float* __restrict__ b6, const float* __restrict__ b7,
        float* __restrict__ usf, float* __restrict__ csf,
        float* __restrict__ b5f, float* __restrict__ b6f, float* __restrict__ b7f,
        float* __restrict__ vvp, int* __restrict__ pairIJ) {
    int tid = threadIdx.x;
    if (tid < 200) {
        int h = (tid >= 100); int e = tid - 100 * h;
        const float* Wa = h ? W3 : W1; const float* Wb = h ? W4 : W2;
        float u = 0.f;
        for (int t = 0; t < 8; t++) u += Wa[t * 100 + e] * Wb[t];
        usf[tid] = u;
    } else if (tid < 202) {
        int h = tid - 200;
        const float* bb = h ? b3 : b1; const float* Wb = h ? W4 : W2;
        float c = 0.f;
        for (int t = 0; t < 8; t++) c += bb[t] * Wb[t];
        csf[h] = c;
    }
    if (tid < 100) {
        b5f[tid] = b5[tid];
        b6f[tid] = b6[tid];
        b7f[tid] = b7[tid];
        int i = tid;
        int base = i * 99 - (i * (i - 1)) / 2;  // start of triu row i (k=1), i-major
        float vi0 = v[i * 4 + 0], vi1 = v[i * 4 + 1];
        float vi2 = v[i * 4 + 2], vi3 = v[i * 4 + 3];
        for (int j = i + 1; j < 100; j++) {
            int p = base + (j - i - 1);
            pairIJ[p] = (i << 8) | j;
            vvp[p] = vi0 * v[j * 4 + 0] + vi1 * v[j * 4 + 1]
                   + vi2 * v[j * 4 + 2] + vi3 * v[j * 4 + 3];
        }
    }
}

// ---------------- K0b: transpose W5,W6,W8 ----------------
__global__ __launch_bounds__(256) void k0b(const float* __restrict__ W5, const float* __restrict__ W6,
        const float* __restrict__ W8, float* __restrict__ W5fT, float* __restrict__ W6fT,
        float* __restrict__ W8fT) {
    int gid = blockIdx.x * 256 + threadIdx.x;
    if (gid < 20000) {                       // W5fT[j][t] = W5[t][j], j<200,t<100
        int o = gid; int j = o / 100; int t = o - 100 * j;
        W5fT[o] = W5[t * 200 + j];
    } else if (gid < 30000) {                // W6fT[j][t] = W6[t][j]
        int o = gid - 20000; int j = o / 100; int t = o - 100 * j;
        W6fT[o] = W6[t * 100 + j];
    } else if (gid < 50000) {                // W8fT[e][u] = W8[u][e], e<200,u<100
        int o = gid - 30000; int e = o / 100; int u = o - 100 * e;
        W8fT[o] = W8[u * 200 + e];
    }
}

// ---------------- K0c: bl8f[l] = sum_u b8[u]*le[u][l];  c8f[u] = sum_t b7[t]*W8[u][100+t] ----
__global__ __launch_bounds__(256) void k0c(const float* __restrict__ b8, const float* __restrict__ le,
                                           const float* __restrict__ b7, const float* __restrict__ W8,
                                           float* __restrict__ bl8f, float* __restrict__ c8f) {
    int gid = blockIdx.x * 256 + threadIdx.x;
    if (gid < L_) {
        float acc = 0.f;
        for (int u = 0; u < 100; u++) acc += b8[u] * le[u * 1000 + gid];
        bl8f[gid] = acc;
    } else if (gid < L_ + 100) {
        int u = gid - L_;
        float acc = 0.f;
        for (int t = 0; t < 100; t++) acc += b7[t] * W8[u * 200 + 100 + t];
        c8f[u] = acc;
    }
}

// ---------------- K0d: W7fT[p][k] = W7[k][p] * vvp[p] (transposed, vv folded) ----------------
__global__ __launch_bounds__(256) void k0d(const float* __restrict__ W7, const float* __restrict__ vvp,
                                           float* __restrict__ W7fT) {
    __shared__ float tile[100 * 65];
    __shared__ float vvs[64];
    int p0 = blockIdx.x * 64;
    int tid = threadIdx.x; int pl = tid & 63;
    int pcnt = min(64, NPAIR - p0);
    if (tid < 64) vvs[tid] = (p0 + tid < NPAIR) ? vvp[p0 + tid] : 0.f;
    __syncthreads();
    for (int kk = tid >> 6; kk < 100; kk += 4) {
        float w = (pl < pcnt) ? W7[kk * NPAIR + p0 + pl] : 0.f;
        tile[kk * 65 + pl] = w * vvs[pl];
    }
    __syncthreads();
    for (int o = tid; o < 6400; o += 256) {
        int pp = o / 100; int k = o - 100 * pp;
        if (pp < pcnt) W7fT[(size_t)(p0 + pp) * 100 + k] = tile[k * 65 + pp];
    }
}

// ---------------- K1: attention pools -> cat1[B][200] ----------------
__global__ __launch_bounds__(256) void k1(const float* __restrict__ x, const float* __restrict__ usf,
                                          const float* __restrict__ csf, float* __restrict__ cat1) {
    __shared__ float xs[N_ * 101];
    __shared__ float zs[2][64];
    __shared__ float wsm[2][64];
    __shared__ float uss[200];
    __shared__ float css[2];
    int b = blockIdx.x; int tid = threadIdx.x;
    const float* xr = x + (size_t)b * (N_ * E_);
    for (int li = tid; li < (N_ * E_) / 4; li += 256) {   // 1250 float4s
        float4 vv = ((const float4*)xr)[li];
        int flat = li * 4; int n = flat / 100; int e = flat - n * 100;
        float* d = xs + n * 101 + e;                       // e<=96, stays in row
        d[0] = vv.x; d[1] = vv.y; d[2] = vv.z; d[3] = vv.w;
    }
    if (tid < 200) uss[tid] = usf[tid];
    if (tid < 2) css[tid] = csf[tid];
    __syncthreads();
    if (tid < 100) {
        int h = (tid >= 50); int n = tid - 50 * h;
        float z = css[h];
        const float* u = uss + h * 100;
        for (int e = 0; e < 100; e++) z = fmaf(xs[n * 101 + e], u[e], z);
        zs[h][n] = expf(z);          // logits = exp(h @ W2^T)
    }
    __syncthreads();
    int wv = tid >> 6, ln = tid & 63;
    if (wv < 2) {
        float a = (ln < 50) ? zs[wv][ln] : -3.0e38f;
        float m = a;
        for (int s = 1; s < 64; s <<= 1) m = fmaxf(m, __shfl_xor(m, s, 64));
        float ex = (ln < 50) ? expf(a - m) : 0.f;
        float ss = ex;
        for (int s = 1; s < 64; s <<= 1) ss += __shfl_xor(ss, s, 64);
        if (ln < 50) wsm[wv][ln] = ex / ss;   // softmax over N
    }
    __syncthreads();
    if (tid < 200) {
        int h = (tid >= 100); int e = tid - 100 * h;
        float q = 0.f;
        for (int n = 0; n < 50; n++) q = fmaf(xs[n * 101 + e], wsm[h][n], q);
        cat1[(size_t)b * 200 + tid] = q;      // [q1 | q2]
    }
}

// ---------------- K2: h5, h6, cross-feature x W7 ----------------
// LDS-pipe-bound at R=1 (round 3: broadcast ds_read_b128 count, not VALU, limits).
// Fix: R=2 register blocking -- 128 batch rows/block, each lane owns rows {lane, 64+lane},
// so every broadcast weight read feeds 56 FMAs instead of 28 (2x fewer DS insts/FMA).
// 1024 threads = 16 waves: phase A/B roles (wk, pg=j-parity, rh=row-half);
// phase C roles (wk, pq=pair-quarter: disjoint 16-pair slices of each 64-pair chunk).
// Grid 64 row-blocks x 4 pair groups = 256 = 1 block/CU, 16 waves/CU.
// Partial-acc combines run through freed wch/sbuf scratch in 2 rounds.
// k-slices 28 wide at {0,28,56,72}; overlap 72..83 computed identically by two waves.
__global__ __launch_bounds__(1024, 4) void k2(const float* __restrict__ cat1,
        const float* __restrict__ W5fT, const float* __restrict__ W6fT,
        const float* __restrict__ b5f, const float* __restrict__ b6f,
        const float* __restrict__ W7fT, const int* __restrict__ pairIJ,
        float* __restrict__ h6T, float* __restrict__ h7Tp) {
    __shared__ float sbuf[128 * 101];                // cat1 half-tile, then h5 tile [128][101]
    __shared__ __align__(16) float wch[2][6400];     // weight chunk dbuf (64 rows x 100); also scratch
    __shared__ int pijc[2][64];
    const int g  = blockIdx.x >> 6;          // pair group 0..3
    const int rb = blockIdx.x & 63;
    const int r0 = rb * 128;
    const int tid = threadIdx.x;
    const int lane = tid & 63;
    const int w = tid >> 6;                  // 0..15
    const int wk = w & 3;
    const int kbase = (wk < 3) ? wk * 28 : 72;
    // phase A/B roles
    const int pg = (w >> 2) & 1;             // j parity
    const int rh = (w >> 3) & 1;             // row half
    const int rowA = rh * 64 + lane;
    const int hbA = rowA * 101;
    // phase C roles
    const int pq = w >> 2;                   // pair quarter 0..3
    const int q16 = pq * 16;
    const int hb1 = lane * 101;
    const int hb2 = (64 + lane) * 101;
    float* wchf = &wch[0][0];

    float acc[28];

    // ================= phase A: h5 = cat1 @ W5^T + b5 =================
    if (pg == 0) {
        const float4* bp = (const float4*)(b5f + kbase);
        #pragma unroll
        for (int q = 0; q < 7; q++) {
            float4 t = bp[q];
            acc[4*q] = t.x; acc[4*q+1] = t.y; acc[4*q+2] = t.z; acc[4*q+3] = t.w;
        }
    } else {
        #pragma unroll
        for (int m = 0; m < 28; m++) acc[m] = 0.f;
    }
    for (int half = 0; half < 2; half++) {
        const float* Wg = W5fT + half * 10000;
        // stage cat1 half-tile -> sbuf (f4 global loads; scalar LDS writes, stride 101)
        for (int o = tid; o < 3200; o += 1024) {
            int r = o / 25; int c = o - r * 25;
            float4 v = ((const float4*)(cat1 + (size_t)(r0 + r) * 200 + half * 100))[c];
            float* d = sbuf + r * 101 + c * 4;
            d[0] = v.x; d[1] = v.y; d[2] = v.z; d[3] = v.w;
        }
        {   // stage weight chunk0 (64 rows)
            const float4* src4 = (const float4*)Wg;
            #pragma unroll
            for (int k = 0; k < 2; k++) {
                int o = tid + (k << 10);
                if (o < 1600) ((float4*)wch[0])[o] = src4[o];
            }
        }
        __syncthreads();
        int cur = 0;
        for (int c2 = 0; c2 < 2; c2++) {
            int rbase = c2 << 6;
            int rc = c2 ? 36 : 64;
            float4 stg; int nf4n = c2 ? 0 : 900;   // next chunk: 36 rows * 25 f4
            { int o = tid; if (o < nf4n) stg = ((const float4*)(Wg + 6400))[o]; }
            const float* wb = wch[cur];
            for (int jj = pg; jj < rc; jj += 2) {
                float s = sbuf[hbA + rbase + jj];
                const float4* wl = (const float4*)(wb + jj * 100 + kbase);
                #pragma unroll
                for (int q = 0; q < 7; q++) {
                    float4 wv = wl[q];
                    acc[4*q]   = fmaf(s, wv.x, acc[4*q]);
                    acc[4*q+1] = fmaf(s, wv.y, acc[4*q+1]);
                    acc[4*q+2] = fmaf(s, wv.z, acc[4*q+2]);
                    acc[4*q+3] = fmaf(s, wv.w, acc[4*q+3]);
                }
            }
            { int o = tid; if (o < nf4n) ((float4*)wch[cur ^ 1])[o] = stg; }
            __syncthreads();
            cur ^= 1;
        }
    }
    // combine j-parity partials (2 rounds by row-half), publish h5 into sbuf
    #pragma unroll 1
    for (int R = 0; R < 2; R++) {
        if (pg == 1 && rh == R) {
            float* d = wchf + (wk * 64 + lane) * 28;
            #pragma unroll
            for (int m = 0; m < 28; m++) d[m] = acc[m];
        }
        __syncthreads();
        if (pg == 0 && rh == R) {
            const float* d = wchf + (wk * 64 + lane) * 28;
            #pragma unroll
            for (int m = 0; m < 28; m++) acc[m] += d[m];
            #pragma unroll
            for (int m = 0; m < 28; m++) sbuf[hbA + kbase + m] = acc[m];
        }
        __syncthreads();
    }

    // ================= phase B: h6 k-slice [g*25, g*25+25) (all blocks, balanced) =========
    {
        const int k0g = g * 25 + ((wk < 3) ? wk * 7 : 18);   // 7-wide, wk=3 overlaps wk=2
        float accB[7];
        if (pg == 0) {
            #pragma unroll
            for (int m = 0; m < 7; m++) accB[m] = b6f[k0g + m];
        } else {
            #pragma unroll
            for (int m = 0; m < 7; m++) accB[m] = 0.f;
        }
        {
            const float4* src4 = (const float4*)W6fT;
            #pragma unroll
            for (int k = 0; k < 2; k++) {
                int o = tid + (k << 10);
                if (o < 1600) ((float4*)wch[0])[o] = src4[o];
            }
        }
        __syncthreads();
        int cur = 0;
        for (int c2 = 0; c2 < 2; c2++) {
            int rbase = c2 << 6;
            int rc = c2 ? 36 : 64;
            float4 stg; int nf4n = c2 ? 0 : 900;
            { int o = tid; if (o < nf4n) stg = ((const float4*)(W6fT + 6400))[o]; }
            const float* wb = wch[cur];
            for (int jj = pg; jj < rc; jj += 2) {
                float s = sbuf[hbA + rbase + jj];
                const float* wl = wb + jj * 100 + k0g;
                #pragma unroll
                for (int m = 0; m < 7; m++) accB[m] = fmaf(s, wl[m], accB[m]);
            }
            { int o = tid; if (o < nf4n) ((float4*)wch[cur ^ 1])[o] = stg; }
            __syncthreads();
            cur ^= 1;
        }
        #pragma unroll 1
        for (int R = 0; R < 2; R++) {
            if (pg == 1 && rh == R) {
                float* d = wchf + (wk * 64 + lane) * 7;
                #pragma unroll
                for (int m = 0; m < 7; m++) d[m] = accB[m];
            }
            __syncthreads();
            if (pg == 0 && rh == R) {
                const float* d = wchf + (wk * 64 + lane) * 7;
                #pragma unroll
                for (int m = 0; m < 7; m++) accB[m] += d[m];
                #pragma unroll
                for (int m = 0; m < 7; m++)
                    h6T[(size_t)(k0g + m) * B_ + r0 + rowA] = accB[m];
            }
            __syncthreads();
        }
    }

    // ================= phase C: h7 partial over this group's pairs (R=2) =================
    float acc2[28];
    #pragma unroll
    for (int m = 0; m < 28; m++) { acc[m] = 0.f; acc2[m] = 0.f; }
    const int pstart = g * 1238;
    const int np = min(NPAIR - pstart, 1238);
    const float* Wg7 = W7fT + (size_t)pstart * 100;
    const int NCH = (np + 63) >> 6;                  // 20
    {
        int rc0 = min(64, np);
        int nf4 = rc0 * 25;
        const float4* src4 = (const float4*)Wg7;
        #pragma unroll
        for (int k = 0; k < 2; k++) {
            int o = tid + (k << 10);
            if (o < nf4) ((float4*)wch[0])[o] = src4[o];
        }
        if (tid < rc0) pijc[0][tid] = pairIJ[pstart + tid];
    }
    __syncthreads();
    int cur = 0;
    int iprev = -1; float vi1 = 0.f, vi2 = 0.f;      // i-run cache (pairs are i-major)
    for (int c = 0; c < NCH; c++) {
        int rbase = c << 6;
        int rc = min(64, np - rbase);
        float4 stg[2]; int pv = 0;
        int rcn = (c + 1 < NCH) ? min(64, np - rbase - 64) : 0;
        int nf4n = rcn * 25;
        const float4* src4 = (const float4*)(Wg7 + (size_t)(rbase + 64) * 100);
        #pragma unroll
        for (int k = 0; k < 2; k++) {
            int o = tid + (k << 10);
            if (o < nf4n) stg[k] = src4[o];
        }
        if (tid < rcn) pv = pairIJ[pstart + rbase + 64 + tid];
        const float* wb = wch[cur];
        int rcq = rc - q16; rcq = rcq < 0 ? 0 : (rcq > 16 ? 16 : rcq);
        for (int r = 0; r < rcq; r++) {
            int ij = pijc[cur][q16 + r];
            int i = ij >> 8, j = ij & 255;
            if (i != iprev) { vi1 = sbuf[hb1 + i]; vi2 = sbuf[hb2 + i]; iprev = i; }
            float sj1 = sbuf[hb1 + j], sj2 = sbuf[hb2 + j];
            float c1 = vi1 * sj1, c2v = vi2 * sj2;
            const float4* wl = (const float4*)(wb + (q16 + r) * 100 + kbase);
            #pragma unroll
            for (int q = 0; q < 7; q++) {
                float4 wv = wl[q];
                acc[4*q]    = fmaf(c1,  wv.x, acc[4*q]);
                acc[4*q+1]  = fmaf(c1,  wv.y, acc[4*q+1]);
                acc[4*q+2]  = fmaf(c1,  wv.z, acc[4*q+2]);
                acc[4*q+3]  = fmaf(c1,  wv.w, acc[4*q+3]);
                acc2[4*q]   = fmaf(c2v, wv.x, acc2[4*q]);
                acc2[4*q+1] = fmaf(c2v, wv.y, acc2[4*q+1]);
                acc2[4*q+2] = fmaf(c2v, wv.z, acc2[4*q+2]);
                acc2[4*q+3] = fmaf(c2v, wv.w, acc2[4*q+3]);
            }
        }
        #pragma unroll
        for (int k = 0; k < 2; k++) {
            int o = tid + (k << 10);
            if (o < nf4n) ((float4*)wch[cur ^ 1])[o] = stg[k];
        }
        if (tid < rcn) pijc[cur ^ 1][tid] = pv;
        __syncthreads();
        cur ^= 1;
    }
    // combine quarter partials (2 rounds: rows r0+lane, then r0+64+lane)
    // scratch: ranks 0..6 in wch flat (7*1792=12544), ranks 7..11 in freed sbuf
    float* h7p = h7Tp + (size_t)g * 100 * B_;
    {
        if (pq != 0) {
            int rank = (pq - 1) * 4 + wk;
            float* d = (rank < 7 ? wchf + rank * 1792 : sbuf + (rank - 7) * 1792) + lane * 28;
            #pragma unroll
            for (int m = 0; m < 28; m++) d[m] = acc[m];
        }
        __syncthreads();
        if (pq == 0) {
            #pragma unroll 1
            for (int t = 0; t < 3; t++) {
                int rank = t * 4 + wk;
                const float* d = (rank < 7 ? wchf + rank * 1792 : sbuf + (rank - 7) * 1792) + lane * 28;
                #pragma unroll
                for (int m = 0; m < 28; m++) acc[m] += d[m];
            }
            #pragma unroll
            for (int m = 0; m < 28; m++)
                h7p[(size_t)(kbase + m) * B_ + r0 + lane] = acc[m];
        }
        __syncthreads();
        if (pq != 0) {
            int rank = (pq - 1) * 4 + wk;
            float* d = (rank < 7 ? wchf + rank * 1792 : sbuf + (rank - 7) * 1792) + lane * 28;
            #pragma unroll
            for (int m = 0; m < 28; m++) d[m] = acc2[m];
        }
        __syncthreads();
        if (pq == 0) {
            #pragma unroll 1
            for (int t = 0; t < 3; t++) {
                int rank = t * 4 + wk;
                const float* d = (rank < 7 ? wchf + rank * 1792 : sbuf + (rank - 7) * 1792) + lane * 28;
                #pragma unroll
                for (int m = 0; m < 28; m++) acc2[m] += d[m];
            }
            #pragma unroll
            for (int m = 0; m < 28; m++)
                h7p[(size_t)(kbase + m) * B_ + r0 + 64 + lane] = acc2[m];
        }
    }
}

// ---------------- K3a: h8T = W8 @ [h6; sum(h7 partials)] + c8 ----------------
// 512 blocks x 256: all CUs active. 16-batch tiles; wave w owns e-range [50w,50w+50);
// lane>>4 owns a 28-wide u-slice {0,28,56,72} (72..83 dup, identical values).
// Waves 1-3 deposit partials in LDS; wave 0 combines, adds c8f, writes.
__global__ __launch_bounds__(256, 2) void k3a(const float* __restrict__ h6T, const float* __restrict__ h7Tp,
        const float* __restrict__ c8f, const float* __restrict__ W8fT, float* __restrict__ h8T) {
    __shared__ float part[3 * 16 * 101];
    int tid = threadIdx.x;
    int lane = tid & 63;
    int w = tid >> 6;
    int bl = lane & 15;
    int ug = lane >> 4;
    int ubase = (ug < 3) ? ug * 28 : 72;
    int b = blockIdx.x * 16 + bl;
    int e0 = w * 50;
    float acc[28];
    #pragma unroll
    for (int m = 0; m < 28; m++) acc[m] = 0.f;
    #pragma unroll 2
    for (int ei = 0; ei < 50; ei++) {
        int e = e0 + ei;
        float vv;
        if (w >= 2) {
            int ee = e - 100;
            vv = h7Tp[(size_t)ee * B_ + b]
               + h7Tp[(size_t)(100 + ee) * B_ + b]
               + h7Tp[(size_t)(200 + ee) * B_ + b]
               + h7Tp[(size_t)(300 + ee) * B_ + b];
        } else {
            vv = h6T[(size_t)e * B_ + b];
        }
        const float4* wp = (const float4*)(W8fT + e * 100 + ubase);
        #pragma unroll
        for (int q = 0; q < 7; q++) {
            float4 wv = wp[q];
            acc[4*q]   = fmaf(vv, wv.x, acc[4*q]);
            acc[4*q+1] = fmaf(vv, wv.y, acc[4*q+1]);
            acc[4*q+2] = fmaf(vv, wv.z, acc[4*q+2]);
            acc[4*q+3] = fmaf(vv, wv.w, acc[4*q+3]);
        }
    }
    if (w >= 1) {
        float* pp = part + (w - 1) * (16 * 101) + bl * 101;
        #pragma unroll
        for (int m = 0; m < 28; m++) pp[ubase + m] = acc[m];
    }
    __syncthreads();
    if (w == 0) {
        const float* p0 = part + bl * 101;
        const float* p1 = part + 16 * 101 + bl * 101;
        const float* p2 = part + 2 * 16 * 101 + bl * 101;
        #pragma unroll
        for (int m = 0; m < 28; m++) {
            float r = acc[m] + p0[ubase + m] + p1[ubase + m] + p2[ubase + m]
                    + c8f[ubase + m];
            h8T[(size_t)(ubase + m) * B_ + b] = r;
        }
    }
}

// ---------------- K3b: out = h8 @ label_embedding (+ b8@le folded bias) ----------------
__global__ __launch_bounds__(256) void k3b(const float* __restrict__ h8T, const float* __restrict__ le,
        const float* __restrict__ bl8f, float* __restrict__ out) {
    int lq = blockIdx.x & 3; int bb = blockIdx.x >> 2;
    int b0 = bb * 32;
    int l = lq * 256 + threadIdx.x;
    bool valid = (l < L_);
    int lc = valid ? l : 0;
    unsigned off0 = 0;
    asm volatile("" : "+v"(off0));           // opaque zero in a VGPR: defeat uniform-addr scalarization
    const float* hb = h8T + b0 + off0;
    float acc[32];
    #pragma unroll
    for (int i = 0; i < 32; i++) acc[i] = 0.f;
    #pragma unroll 2
    for (int u = 0; u < 100; u++) {
        float lev = le[u * 1000 + lc];
        const float4* hp = (const float4*)(hb + (size_t)u * B_);
        #pragma unroll
        for (int q = 0; q < 8; q++) {
            float4 hv = hp[q];
            acc[4*q]   = fmaf(hv.x, lev, acc[4*q]);
            acc[4*q+1] = fmaf(hv.y, lev, acc[4*q+1]);
            acc[4*q+2] = fmaf(hv.z, lev, acc[4*q+2]);
            acc[4*q+3] = fmaf(hv.w, lev, acc[4*q+3]);
        }
    }
    if (valid) {
        float bias = bl8f[l];
        #pragma unroll
        for (int i = 0; i < 32; i++)
            out[(size_t)(b0 + i) * 1000 + l] = acc[i] + bias;
    }
}

extern "C" void kernel_launch(void* const* d_in, const int* in_sizes, int n_in,
                              void* d_out, int out_size, void* d_ws, size_t ws_size,
                              hipStream_t stream) {
    const float* x  = (const float*)d_in[0];
    const float* v  = (const float*)d_in[1];
    const float* W1 = (const float*)d_in[2];
    const float* b1 = (const float*)d_in[3];
    const float* W2 = (const float*)d_in[4];
    const float* W3 = (const float*)d_in[5];
    const float* b3 = (const float*)d_in[6];
    const float* W4 = (const float*)d_in[7];
    const float* W5 = (const float*)d_in[8];
    const float* b5 = (const float*)d_in[9];
    const float* W6 = (const float*)d_in[10];
    const float* b6 = (const float*)d_in[11];
    const float* W7 = (const float*)d_in[12];
    const float* b7 = (const float*)d_in[13];
    const float* W8 = (const float*)d_in[14];
    const float* b8 = (const float*)d_in[15];
    const float* le = (const float*)d_in[16];
    float* out = (float*)d_out;
    float* ws = (float*)d_ws;

    float* cat1   = ws;                 // 1,638,400
    float* h6T    = ws + 1638400;       //   819,200
    float* h7Tp   = ws + 2457600;       // 3,276,800 (4 partials x 100 x B)
    float* h8T    = ws + 5734400;       //   819,200
    float* W7fT   = ws + 6553600;       //   495,000
    float* W5fT   = ws + 7048600;       //    20,000
    float* W6fT   = ws + 7068600;       //    10,000
    float* W8fT   = ws + 7078600;       //    20,000
    float* usf    = ws + 7098600;       //       200
    float* csf    = ws + 7098800;       //       2 (+2 pad)
    float* b5f    = ws + 7098804;       //       100
    float* b6f    = ws + 7098904;       //       100
    float* b7f    = ws + 7099004;       //       100
    float* bl8f   = ws + 7099104;       //      1000
    float* vvp    = ws + 7100104;       //      4950
    int*   pairIJ = (int*)(ws + 7105054); //    4950
    float* c8f    = ws + 7110004;       //       100

    k0a<<<1, 256, 0, stream>>>(v, W1, b1, W2, W3, b3, W4, b5, b6, b7,
                               usf, csf, b5f, b6f, b7f, vvp, pairIJ);
    k0b<<<196, 256, 0, stream>>>(W5, W6, W8, W5fT, W6fT, W8fT);
    k0c<<<5, 256, 0, stream>>>(b8, le, b7, W8, bl8f, c8f);
    k0d<<<78, 256, 0, stream>>>(W7, vvp, W7fT);
    k1<<<8192, 256, 0, stream>>>(x, usf, csf, cat1);
    k2<<<256, 1024, 0, stream>>>(cat1, W5fT, W6fT, b5f, b6f, W7fT, pairIJ, h6T, h7Tp);
    k3a<<<512, 256, 0, stream>>>(h6T, h7Tp, c8f, W8fT, h8T);
    k3b<<<1024, 256, 0, stream>>>(h8T, le, bl8f, out);
}

// Round 5
// 533.579 us; speedup vs baseline: 1.9741x; 1.1971x over previous
//
#include <hip/hip_runtime.h>
#include <cstdint>
#include <cstddef>

#define E_    100
#define N_    50
#define B_    8192
#define L_    1000
#define NPAIR 4950

typedef __attribute__((ext_vector_type(8))) short short8v;   // 8 bf16 (4 VGPR)
typedef __attribute__((ext_vector_type(4))) float f32x4;

// split f32 -> bf16 hi + bf16 lo (RTNE both): x ~= hi + lo to ~2^-17 rel
__device__ __forceinline__ void bfsplit(float x, unsigned& h, unsigned& l) {
    unsigned b = __float_as_uint(x);
    unsigned rh = b + 0x7FFFu + ((b >> 16) & 1u);
    h = rh >> 16;
    float fh = __uint_as_float(h << 16);
    float r = x - fh;
    unsigned b2 = __float_as_uint(r);
    unsigned rl = b2 + 0x7FFFu + ((b2 >> 16) & 1u);
    l = rl >> 16;
}

// ---------------- K0: merged tiny precomputes ----------------
// block 0: attention u/c vectors, bias copies, pair table, vv
// blocks 1..196: transpose W5,W6,W8
// blocks 197..201: bl8f, c8f
__global__ __launch_bounds__(256) void k0(const float* __restrict__ v,
        const float* __restrict__ W1, const float* __restrict__ b1, const float* __restrict__ W2,
        const float* __restrict__ W3, const float* __restrict__ b3, const float* __restrict__ W4,
        const float* __restrict__ W5, const float* __restrict__ W6, const float* __restrict__ W8,
        const float* __restrict__ b5, const float* __restrict__ b6, const float* __restrict__ b7,
        const float* __restrict__ b8, const float* __restrict__ le,
        float* __restrict__ usf, float* __restrict__ csf,
        float* __restrict__ b5f, float* __restrict__ b6f, float* __restrict__ b7f,
        float* __restrict__ vvp, int* __restrict__ pairIJ,
        float* __restrict__ W5fT, float* __restrict__ W6fT, float* __restrict__ W8fT,
        float* __restrict__ bl8f, float* __restrict__ c8f) {
    int b = blockIdx.x;
    int tid = threadIdx.x;
    if (b == 0) {
        if (tid < 200) {
            int h = (tid >= 100); int e = tid - 100 * h;
            const float* Wa = h ? W3 : W1; const float* Wb = h ? W4 : W2;
            float u = 0.f;
            for (int t = 0; t < 8; t++) u += Wa[t * 100 + e] * Wb[t];
            usf[tid] = u;
        } else if (tid < 202) {
            int h = tid - 200;
            const float* bb = h ? b3 : b1; const float* Wb = h ? W4 : W2;
            float c = 0.f;
            for (int t = 0; t < 8; t++) c += bb[t] * Wb[t];
            csf[h] = c;
        }
        if (tid < 100) {
            b5f[tid] = b5[tid];
            b6f[tid] = b6[tid];
            b7f[tid] = b7[tid];
            int i = tid;
            int base = i * 99 - (i * (i - 1)) / 2;  // start of triu row i (k=1), i-major
            float vi0 = v[i * 4 + 0], vi1 = v[i * 4 + 1];
            float vi2 = v[i * 4 + 2], vi3 = v[i * 4 + 3];
            for (int j = i + 1; j < 100; j++) {
                int p = base + (j - i - 1);
                pairIJ[p] = (i << 8) | j;
                vvp[p] = vi0 * v[j * 4 + 0] + vi1 * v[j * 4 + 1]
                       + vi2 * v[j * 4 + 2] + vi3 * v[j * 4 + 3];
            }
        }
    } else if (b <= 196) {
        int gid = (b - 1) * 256 + tid;
        if (gid < 20000) {                       // W5fT[j][t] = W5[t][j]
            int o = gid; int j = o / 100; int t = o - 100 * j;
            W5fT[o] = W5[t * 200 + j];
        } else if (gid < 30000) {                // W6fT[j][t] = W6[t][j]
            int o = gid - 20000; int j = o / 100; int t = o - 100 * j;
            W6fT[o] = W6[t * 100 + j];
        } else if (gid < 50000) {                // W8fT[e][u] = W8[u][e]
            int o = gid - 30000; int e = o / 100; int u = o - 100 * e;
            W8fT[o] = W8[u * 200 + e];
        }
    } else {
        int gid = (b - 197) * 256 + tid;
        if (gid < L_) {
            float acc = 0.f;
            for (int u = 0; u < 100; u++) acc += b8[u] * le[u * 1000 + gid];
            bl8f[gid] = acc;
        } else if (gid < L_ + 100) {
            int u = gid - L_;
            float acc = 0.f;
            for (int t = 0; t < 100; t++) acc += b7[t] * W8[u * 200 + 100 + t];
            c8f[u] = acc;
        }
    }
}

// ---------------- K0d2: build W7b = split-bf16, MFMA-B-fragment layout ----------------
// Per (group g, chunk c of 32 pairs): [2 (hi/lo)][112 n][40 k] bf16 (ushort bits),
// n>=100 / k>=32 / invalid pairs zeroed. w = W7[n][p] * vv[p] folded.
__global__ __launch_bounds__(256) void k0d2(const float* __restrict__ W7, const float* __restrict__ vvp,
                                            ushort* __restrict__ W7b) {
    int bc = blockIdx.x;
    int g = bc / 39, c = bc - 39 * g;
    int p0 = g * 1238 + c * 32;
    int pend = min(NPAIR, g * 1238 + 1238);
    ushort* dst = W7b + (size_t)bc * 8960;
    for (int idx = threadIdx.x; idx < 4480; idx += 256) {
        int n = idx / 40, k = idx - 40 * n;
        int p = p0 + k;
        float wv = 0.f;
        if (n < 100 && k < 32 && p < pend) wv = W7[n * NPAIR + p] * vvp[p];
        unsigned h, l;
        bfsplit(wv, h, l);
        dst[idx] = (ushort)h;
        dst[4480 + idx] = (ushort)l;
    }
}

// ---------------- K1: attention pools -> cat1[B][200] ----------------
__global__ __launch_bounds__(256) void k1(const float* __restrict__ x, const float* __restrict__ usf,
                                          const float* __restrict__ csf, float* __restrict__ cat1) {
    __shared__ float xs[N_ * 101];
    __shared__ float zs[2][64];
    __shared__ float wsm[2][64];
    __shared__ float uss[200];
    __shared__ float css[2];
    int b = blockIdx.x; int tid = threadIdx.x;
    const float* xr = x + (size_t)b * (N_ * E_);
    for (int li = tid; li < (N_ * E_) / 4; li += 256) {   // 1250 float4s
        float4 vv = ((const float4*)xr)[li];
        int flat = li * 4; int n = flat / 100; int e = flat - n * 100;
        float* d = xs + n * 101 + e;                       // e<=96, stays in row
        d[0] = vv.x; d[1] = vv.y; d[2] = vv.z; d[3] = vv.w;
    }
    if (tid < 200) uss[tid] = usf[tid];
    if (tid < 2) css[tid] = csf[tid];
    __syncthreads();
    if (tid < 100) {
        int h = (tid >= 50); int n = tid - 50 * h;
        float z = css[h];
        const float* u = uss + h * 100;
        for (int e = 0; e < 100; e++) z = fmaf(xs[n * 101 + e], u[e], z);
        zs[h][n] = expf(z);          // logits = exp(h @ W2^T)
    }
    __syncthreads();
    int wv = tid >> 6, ln = tid & 63;
    if (wv < 2) {
        float a = (ln < 50) ? zs[wv][ln] : -3.0e38f;
        float m = a;
        for (int s = 1; s < 64; s <<= 1) m = fmaxf(m, __shfl_xor(m, s, 64));
        float ex = (ln < 50) ? expf(a - m) : 0.f;
        float ss = ex;
        for (int s = 1; s < 64; s <<= 1) ss += __shfl_xor(ss, s, 64);
        if (ln < 50) wsm[wv][ln] = ex / ss;   // softmax over N
    }
    __syncthreads();
    if (tid < 200) {
        int h = (tid >= 100); int e = tid - 100 * h;
        float q = 0.f;
        for (int n = 0; n < 50; n++) q = fmaf(xs[n * 101 + e], wsm[h][n], q);
        cat1[(size_t)b * 200 + tid] = q;      // [q1 | q2]
    }
}

// ---------------- K2: h5, h6 (vector, round-4 structure) + h7 via MFMA split-bf16 ----------------
// Phase C is a dense GEMM h7[128x100] += cf[128x1238] @ W7'[1238x100]; round-4 vector version
// was LDS+VALU bound (~150us). Now: per 32-pair chunk, build A-tile (cf split to bf16 hi/lo,
// [8 mt][16 m][40 k]) in LDS; B staged from precomputed W7b ([112 n][40 k] hi/lo, dbuf);
// 16 waves = (mt 0..7) x (nh 0..1) run mfma_f32_16x16x32_bf16: ch*wh + ch*wl + cl*wh
// (cl*wl dropped: ~2^-16 rel). C/D layout col=lane&15,row=(lane>>4)*4+reg -> float4 stores.
__global__ __launch_bounds__(1024, 4) void k2(const float* __restrict__ cat1,
        const float* __restrict__ W5fT, const float* __restrict__ W6fT,
        const float* __restrict__ b5f, const float* __restrict__ b6f,
        const ushort* __restrict__ W7b, const int* __restrict__ pairIJ,
        float* __restrict__ h6T, float* __restrict__ h7Tp) {
    __shared__ float sbuf[128 * 101];                  // cat1 half-tile, then h5 tile
    __shared__ __align__(16) ushort scratch2[28672];   // phase A/B: f32 weight dbuf (51.2KB)
                                                       // phase C: Ach[5120] Acl[5120] Bb0[8960] Bb1[8960]
    __shared__ int pijc2[2][32];
    const int g  = blockIdx.x >> 6;          // pair group 0..3
    const int rb = blockIdx.x & 63;
    const int r0 = rb * 128;
    const int tid = threadIdx.x;
    const int lane = tid & 63;
    const int w = tid >> 6;                  // 0..15
    const int wk = w & 3;
    const int kbase = (wk < 3) ? wk * 28 : 72;
    // phase A/B roles
    const int pg = (w >> 2) & 1;             // j parity
    const int rh = (w >> 3) & 1;             // row half
    const int rowA = rh * 64 + lane;
    const int hbA = rowA * 101;
    // phase C roles
    const int mt = w >> 1;                   // M-tile 0..7
    const int nh = w & 1;                    // N-half: 0 -> nt 0..3, 1 -> nt 4..6
    float* wchA0 = (float*)scratch2;
    float* wchA1 = wchA0 + 6400;
    float* wchf  = wchA0;

    float acc[28];

    // ================= phase A: h5 = cat1 @ W5^T + b5 (unchanged from round 4) ==========
    if (pg == 0) {
        const float4* bp = (const float4*)(b5f + kbase);
        #pragma unroll
        for (int q = 0; q < 7; q++) {
            float4 t = bp[q];
            acc[4*q] = t.x; acc[4*q+1] = t.y; acc[4*q+2] = t.z; acc[4*q+3] = t.w;
        }
    } else {
        #pragma unroll
        for (int m = 0; m < 28; m++) acc[m] = 0.f;
    }
    for (int half = 0; half < 2; half++) {
        const float* Wg = W5fT + half * 10000;
        for (int o = tid; o < 3200; o += 1024) {
            int r = o / 25; int c = o - r * 25;
            float4 v = ((const float4*)(cat1 + (size_t)(r0 + r) * 200 + half * 100))[c];
            float* d = sbuf + r * 101 + c * 4;
            d[0] = v.x; d[1] = v.y; d[2] = v.z; d[3] = v.w;
        }
        {
            const float4* src4 = (const float4*)Wg;
            #pragma unroll
            for (int k = 0; k < 2; k++) {
                int o = tid + (k << 10);
                if (o < 1600) ((float4*)wchA0)[o] = src4[o];
            }
        }
        __syncthreads();
        int cur = 0;
        for (int c2 = 0; c2 < 2; c2++) {
            int rbase = c2 << 6;
            int rc = c2 ? 36 : 64;
            float4 stg; int nf4n = c2 ? 0 : 900;
            { int o = tid; if (o < nf4n) stg = ((const float4*)(Wg + 6400))[o]; }
            const float* wb = cur ? wchA1 : wchA0;
            for (int jj = pg; jj < rc; jj += 2) {
                float s = sbuf[hbA + rbase + jj];
                const float4* wl = (const float4*)(wb + jj * 100 + kbase);
                #pragma unroll
                for (int q = 0; q < 7; q++) {
                    float4 wv = wl[q];
                    acc[4*q]   = fmaf(s, wv.x, acc[4*q]);
                    acc[4*q+1] = fmaf(s, wv.y, acc[4*q+1]);
                    acc[4*q+2] = fmaf(s, wv.z, acc[4*q+2]);
                    acc[4*q+3] = fmaf(s, wv.w, acc[4*q+3]);
                }
            }
            { int o = tid; if (o < nf4n) ((float4*)(cur ? wchA0 : wchA1))[o] = stg; }
            __syncthreads();
            cur ^= 1;
        }
    }
    // combine j-parity partials, publish h5 into sbuf
    #pragma unroll 1
    for (int R = 0; R < 2; R++) {
        if (pg == 1 && rh == R) {
            float* d = wchf + (wk * 64 + lane) * 28;
            #pragma unroll
            for (int m = 0; m < 28; m++) d[m] = acc[m];
        }
        __syncthreads();
        if (pg == 0 && rh == R) {
            const float* d = wchf + (wk * 64 + lane) * 28;
            #pragma unroll
            for (int m = 0; m < 28; m++) acc[m] += d[m];
            #pragma unroll
            for (int m = 0; m < 28; m++) sbuf[hbA + kbase + m] = acc[m];
        }
        __syncthreads();
    }

    // ================= phase B: h6 k-slice [g*25, g*25+25) (unchanged from round 4) =====
    {
        const int k0g = g * 25 + ((wk < 3) ? wk * 7 : 18);
        float accB[7];
        if (pg == 0) {
            #pragma unroll
            for (int m = 0; m < 7; m++) accB[m] = b6f[k0g + m];
        } else {
            #pragma unroll
            for (int m = 0; m < 7; m++) accB[m] = 0.f;
        }
        {
            const float4* src4 = (const float4*)W6fT;
            #pragma unroll
            for (int k = 0; k < 2; k++) {
                int o = tid + (k << 10);
                if (o < 1600) ((float4*)wchA0)[o] = src4[o];
            }
        }
        __syncthreads();
        int cur = 0;
        for (int c2 = 0; c2 < 2; c2++) {
            int rbase = c2 << 6;
            int rc = c2 ? 36 : 64;
            float4 stg; int nf4n = c2 ? 0 : 900;
            { int o = tid; if (o < nf4n) stg = ((const float4*)(W6fT + 6400))[o]; }
            const float* wb = cur ? wchA1 : wchA0;
            for (int jj = pg; jj < rc; jj += 2) {
                float s = sbuf[hbA + rbase + jj];
                const float* wl = wb + jj * 100 + k0g;
                #pragma unroll
                for (int m = 0; m < 7; m++) accB[m] = fmaf(s, wl[m], accB[m]);
            }
            { int o = tid; if (o < nf4n) ((float4*)(cur ? wchA0 : wchA1))[o] = stg; }
            __syncthreads();
            cur ^= 1;
        }
        #pragma unroll 1
        for (int R = 0; R < 2; R++) {
            if (pg == 1 && rh == R) {
                float* d = wchf + (wk * 64 + lane) * 7;
                #pragma unroll
                for (int m = 0; m < 7; m++) d[m] = accB[m];
            }
            __syncthreads();
            if (pg == 0 && rh == R) {
                const float* d = wchf + (wk * 64 + lane) * 7;
                #pragma unroll
                for (int m = 0; m < 7; m++) accB[m] += d[m];
                #pragma unroll
                for (int m = 0; m < 7; m++)
                    h6T[(size_t)(k0g + m) * B_ + r0 + rowA] = accB[m];
            }
            __syncthreads();
        }
    }

    // ================= phase C: h7 = cf @ W7' via MFMA (split-bf16) =================
    const int pstart = g * 1238;
    const int pend = min(NPAIR, pstart + 1238);
    const ushort* W7g = W7b + (size_t)(g * 39) * 8960;
    ushort* Ach = scratch2;            // [8][16][40]
    ushort* Acl = scratch2 + 5120;
    ushort* Bb0 = scratch2 + 10240;    // [2][112][40] per chunk, dbuf
    ushort* Bb1 = scratch2 + 19200;
    // prologue: stage chunk 0
    {
        const float4* src = (const float4*)W7g;
        for (int o = tid; o < 1120; o += 1024) ((float4*)Bb0)[o] = src[o];
        if (tid < 32) { int p = pstart + tid; pijc2[0][tid] = (p < pend) ? pairIJ[p] : 1; }
    }
    __syncthreads();
    f32x4 accv[4];
    #pragma unroll
    for (int q = 0; q < 4; q++) accv[q] = (f32x4){0.f, 0.f, 0.f, 0.f};
    int cur = 0;
    const int lm = lane & 15;
    const int lko = (lane >> 4) << 3;
    const int p2 = (tid & 15) * 2;
    const int rb2 = (tid >> 4) * 2;
    for (int c = 0; c < 39; c++) {
        // issue-early: next B chunk + pair table into regs (T14)
        float4 s0, s1; int pvN = 1;
        if (c < 38) {
            const float4* src = (const float4*)(W7g + (size_t)(c + 1) * 8960);
            s0 = src[tid];
            if (tid < 96) s1 = src[tid + 1024];
            if (tid < 32) { int p = pstart + (c + 1) * 32 + tid; pvN = (p < pend) ? pairIJ[p] : 1; }
        }
        // cf-build for chunk c: 4 elems/thread (2 rows x 2 pairs), split + pack
        {
            int ij0 = pijc2[cur][p2];
            int ij1 = pijc2[cur][p2 + 1];
            int i0 = ij0 >> 8, j0 = ij0 & 255;
            int i1 = ij1 >> 8, j1 = ij1 & 255;
            #pragma unroll
            for (int rr = 0; rr < 2; rr++) {
                int r = rb2 + rr;
                const float* hr = sbuf + r * 101;
                float a0 = hr[i0] * hr[j0];
                float a1 = hr[i1] * hr[j1];
                unsigned h0, l0, h1, l1;
                bfsplit(a0, h0, l0);
                bfsplit(a1, h1, l1);
                int idx = (r >> 4) * 640 + (r & 15) * 40 + p2;
                *(unsigned*)(Ach + idx) = h0 | (h1 << 16);
                *(unsigned*)(Acl + idx) = l0 | (l1 << 16);
            }
        }
        __syncthreads();
        // MFMA: D = A(cf) x B(W7'), 3-term split
        {
            const ushort* Bc = cur ? Bb1 : Bb0;
            int ab = mt * 640 + lm * 40 + lko;
            short8v aH = *(const short8v*)(Ach + ab);
            short8v aL = *(const short8v*)(Acl + ab);
            #pragma unroll
            for (int q = 0; q < 4; q++) {
                if (!(nh && q == 3)) {
                    int nt = nh * 4 + q;
                    const ushort* bp = Bc + (nt * 16 + lm) * 40 + lko;
                    short8v bH = *(const short8v*)bp;
                    short8v bL = *(const short8v*)(bp + 4480);
                    accv[q] = __builtin_amdgcn_mfma_f32_16x16x32_bf16(aH, bH, accv[q], 0, 0, 0);
                    accv[q] = __builtin_amdgcn_mfma_f32_16x16x32_bf16(aH, bL, accv[q], 0, 0, 0);
                    accv[q] = __builtin_amdgcn_mfma_f32_16x16x32_bf16(aL, bH, accv[q], 0, 0, 0);
                }
            }
        }
        // write-late staged B
        if (c < 38) {
            ushort* Bn = cur ? Bb0 : Bb1;
            ((float4*)Bn)[tid] = s0;
            if (tid < 96) ((float4*)Bn)[tid + 1024] = s1;
            if (tid < 32) pijc2[cur ^ 1][tid] = pvN;
        }
        __syncthreads();
        cur ^= 1;
    }
    // epilogue: coalesced float4 stores (C/D rows (lane>>4)*4+reg are vector-contiguous)
    {
        float* h7p = h7Tp + (size_t)g * 100 * B_;
        int rowb = r0 + mt * 16 + ((lane >> 4) << 2);
        #pragma unroll
        for (int q = 0; q < 4; q++) {
            if (!(nh && q == 3)) {
                int col = (nh * 4 + q) * 16 + lm;
                if (col < 100) {
                    float4 o4;
                    o4.x = accv[q][0]; o4.y = accv[q][1]; o4.z = accv[q][2]; o4.w = accv[q][3];
                    *(float4*)(h7p + (size_t)col * B_ + rowb) = o4;
                }
            }
        }
    }
}

// ---------------- K3a: h8T = W8 @ [h6; sum(h7 partials)] + c8 (unchanged) ----------------
__global__ __launch_bounds__(256, 2) void k3a(const float* __restrict__ h6T, const float* __restrict__ h7Tp,
        const float* __restrict__ c8f, const float* __restrict__ W8fT, float* __restrict__ h8T) {
    __shared__ float part[3 * 16 * 101];
    int tid = threadIdx.x;
    int lane = tid & 63;
    int w = tid >> 6;
    int bl = lane & 15;
    int ug = lane >> 4;
    int ubase = (ug < 3) ? ug * 28 : 72;
    int b = blockIdx.x * 16 + bl;
    int e0 = w * 50;
    float acc[28];
    #pragma unroll
    for (int m = 0; m < 28; m++) acc[m] = 0.f;
    #pragma unroll 2
    for (int ei = 0; ei < 50; ei++) {
        int e = e0 + ei;
        float vv;
        if (w >= 2) {
            int ee = e - 100;
            vv = h7Tp[(size_t)ee * B_ + b]
               + h7Tp[(size_t)(100 + ee) * B_ + b]
               + h7Tp[(size_t)(200 + ee) * B_ + b]
               + h7Tp[(size_t)(300 + ee) * B_ + b];
        } else {
            vv = h6T[(size_t)e * B_ + b];
        }
        const float4* wp = (const float4*)(W8fT + e * 100 + ubase);
        #pragma unroll
        for (int q = 0; q < 7; q++) {
            float4 wv = wp[q];
            acc[4*q]   = fmaf(vv, wv.x, acc[4*q]);
            acc[4*q+1] = fmaf(vv, wv.y, acc[4*q+1]);
            acc[4*q+2] = fmaf(vv, wv.z, acc[4*q+2]);
            acc[4*q+3] = fmaf(vv, wv.w, acc[4*q+3]);
        }
    }
    if (w >= 1) {
        float* pp = part + (w - 1) * (16 * 101) + bl * 101;
        #pragma unroll
        for (int m = 0; m < 28; m++) pp[ubase + m] = acc[m];
    }
    __syncthreads();
    if (w == 0) {
        const float* p0 = part + bl * 101;
        const float* p1 = part + 16 * 101 + bl * 101;
        const float* p2 = part + 2 * 16 * 101 + bl * 101;
        #pragma unroll
        for (int m = 0; m < 28; m++) {
            float r = acc[m] + p0[ubase + m] + p1[ubase + m] + p2[ubase + m]
                    + c8f[ubase + m];
            h8T[(size_t)(ubase + m) * B_ + b] = r;
        }
    }
}

// ---------------- K3b: out = h8 @ label_embedding (+ b8@le folded bias) (unchanged) ------
__global__ __launch_bounds__(256) void k3b(const float* __restrict__ h8T, const float* __restrict__ le,
        const float* __restrict__ bl8f, float* __restrict__ out) {
    int lq = blockIdx.x & 3; int bb = blockIdx.x >> 2;
    int b0 = bb * 32;
    int l = lq * 256 + threadIdx.x;
    bool valid = (l < L_);
    int lc = valid ? l : 0;
    unsigned off0 = 0;
    asm volatile("" : "+v"(off0));           // opaque zero in a VGPR: defeat uniform-addr scalarization
    const float* hb = h8T + b0 + off0;
    float acc[32];
    #pragma unroll
    for (int i = 0; i < 32; i++) acc[i] = 0.f;
    #pragma unroll 2
    for (int u = 0; u < 100; u++) {
        float lev = le[u * 1000 + lc];
        const float4* hp = (const float4*)(hb + (size_t)u * B_);
        #pragma unroll
        for (int q = 0; q < 8; q++) {
            float4 hv = hp[q];
            acc[4*q]   = fmaf(hv.x, lev, acc[4*q]);
            acc[4*q+1] = fmaf(hv.y, lev, acc[4*q+1]);
            acc[4*q+2] = fmaf(hv.z, lev, acc[4*q+2]);
            acc[4*q+3] = fmaf(hv.w, lev, acc[4*q+3]);
        }
    }
    if (valid) {
        float bias = bl8f[l];
        #pragma unroll
        for (int i = 0; i < 32; i++)
            out[(size_t)(b0 + i) * 1000 + l] = acc[i] + bias;
    }
}

extern "C" void kernel_launch(void* const* d_in, const int* in_sizes, int n_in,
                              void* d_out, int out_size, void* d_ws, size_t ws_size,
                              hipStream_t stream) {
    const float* x  = (const float*)d_in[0];
    const float* v  = (const float*)d_in[1];
    const float* W1 = (const float*)d_in[2];
    const float* b1 = (const float*)d_in[3];
    const float* W2 = (const float*)d_in[4];
    const float* W3 = (const float*)d_in[5];
    const float* b3 = (const float*)d_in[6];
    const float* W4 = (const float*)d_in[7];
    const float* W5 = (const float*)d_in[8];
    const float* b5 = (const float*)d_in[9];
    const float* W6 = (const float*)d_in[10];
    const float* b6 = (const float*)d_in[11];
    const float* W7 = (const float*)d_in[12];
    const float* b7 = (const float*)d_in[13];
    const float* W8 = (const float*)d_in[14];
    const float* b8 = (const float*)d_in[15];
    const float* le = (const float*)d_in[16];
    float* out = (float*)d_out;
    float* ws = (float*)d_ws;

    float* cat1   = ws;                 // 1,638,400
    float* h6T    = ws + 1638400;       //   819,200
    float* h7Tp   = ws + 2457600;       // 3,276,800 (4 partials x 100 x B)
    float* h8T    = ws + 5734400;       //   819,200  (W7b aliases this pre-k3a)
    // ws + 6553600 .. : 495,000 slot free (old W7fT, unused)
    float* W5fT   = ws + 7048600;       //    20,000
    float* W6fT   = ws + 7068600;       //    10,000
    float* W8fT   = ws + 7078600;       //    20,000
    float* usf    = ws + 7098600;       //       200
    float* csf    = ws + 7098800;       //       2 (+2 pad)
    float* b5f    = ws + 7098804;       //       100
    float* b6f    = ws + 7098904;       //       100
    float* b7f    = ws + 7099004;       //       100
    float* bl8f   = ws + 7099104;       //      1000
    float* vvp    = ws + 7100104;       //      4950
    int*   pairIJ = (int*)(ws + 7105054); //    4950
    float* c8f    = ws + 7110004;       //       100
    // W7b: 156 chunks x 8960 ushort = 1,397,760 ushort = 698,880 f32 <= h8T's 819,200.
    // Written by k0d2 (before k2), dead after k2; h8T written by k3a (after k2). No overlap in time.
    ushort* W7b   = (ushort*)h8T;

    k0<<<202, 256, 0, stream>>>(v, W1, b1, W2, W3, b3, W4, W5, W6, W8, b5, b6, b7, b8, le,
                                usf, csf, b5f, b6f, b7f, vvp, pairIJ,
                                W5fT, W6fT, W8fT, bl8f, c8f);
    k0d2<<<156, 256, 0, stream>>>(W7, vvp, W7b);
    k1<<<8192, 256, 0, stream>>>(x, usf, csf, cat1);
    k2<<<256, 1024, 0, stream>>>(cat1, W5fT, W6fT, b5f, b6f, W7b, pairIJ, h6T, h7Tp);
    k3a<<<512, 256, 0, stream>>>(h6T, h7Tp, c8f, W8fT, h8T);
    k3b<<<1024, 256, 0, stream>>>(h8T, le, bl8f, out);
}

// Round 7
// 425.167 us; speedup vs baseline: 2.4775x; 1.2550x over previous
//
#include <hip/hip_runtime.h>
#include <cstdint>
#include <cstddef>

#define E_    100
#define N_    50
#define B_    8192
#define L_    1000
#define NPAIR 4950

typedef __attribute__((ext_vector_type(8))) short short8v;   // 8 bf16 (4 VGPR)
typedef __attribute__((ext_vector_type(4))) float f32x4;

// split f32 -> bf16 hi + bf16 lo (RTNE both): x ~= hi + lo to ~2^-17 rel
__device__ __forceinline__ void bfsplit(float x, unsigned& h, unsigned& l) {
    unsigned b = __float_as_uint(x);
    unsigned rh = b + 0x7FFFu + ((b >> 16) & 1u);
    h = rh >> 16;
    float fh = __uint_as_float(h << 16);
    float r = x - fh;
    unsigned b2 = __float_as_uint(r);
    unsigned rl = b2 + 0x7FFFu + ((b2 >> 16) & 1u);
    l = rl >> 16;
}

// ---------------- K0: merged tiny precomputes ----------------
__global__ __launch_bounds__(256) void k0(const float* __restrict__ v,
        const float* __restrict__ W1, const float* __restrict__ b1, const float* __restrict__ W2,
        const float* __restrict__ W3, const float* __restrict__ b3, const float* __restrict__ W4,
        const float* __restrict__ W5, const float* __restrict__ W6, const float* __restrict__ W8,
        const float* __restrict__ b5, const float* __restrict__ b6, const float* __restrict__ b7,
        const float* __restrict__ b8, const float* __restrict__ le,
        float* __restrict__ usf, float* __restrict__ csf,
        float* __restrict__ b5f, float* __restrict__ b6f,
        float* __restrict__ vvp, int* __restrict__ pairIJ,
        float* __restrict__ W5fT, float* __restrict__ W6fT, float* __restrict__ W8fT,
        float* __restrict__ bl8f, float* __restrict__ c8f) {
    int b = blockIdx.x;
    int tid = threadIdx.x;
    if (b == 0) {
        if (tid < 200) {
            int h = (tid >= 100); int e = tid - 100 * h;
            const float* Wa = h ? W3 : W1; const float* Wb = h ? W4 : W2;
            float u = 0.f;
            for (int t = 0; t < 8; t++) u += Wa[t * 100 + e] * Wb[t];
            usf[tid] = u;
        } else if (tid < 202) {
            int h = tid - 200;
            const float* bb = h ? b3 : b1; const float* Wb = h ? W4 : W2;
            float c = 0.f;
            for (int t = 0; t < 8; t++) c += bb[t] * Wb[t];
            csf[h] = c;
        }
        if (tid < 100) {
            b5f[tid] = b5[tid];
            b6f[tid] = b6[tid];
            int i = tid;
            int base = i * 99 - (i * (i - 1)) / 2;  // start of triu row i (k=1), i-major
            float vi0 = v[i * 4 + 0], vi1 = v[i * 4 + 1];
            float vi2 = v[i * 4 + 2], vi3 = v[i * 4 + 3];
            for (int j = i + 1; j < 100; j++) {
                int p = base + (j - i - 1);
                pairIJ[p] = (i << 8) | j;
                vvp[p] = vi0 * v[j * 4 + 0] + vi1 * v[j * 4 + 1]
                       + vi2 * v[j * 4 + 2] + vi3 * v[j * 4 + 3];
            }
        }
    } else if (b <= 196) {
        int gid = (b - 1) * 256 + tid;
        if (gid < 20000) {                       // W5fT[j][t] = W5[t][j]
            int o = gid; int j = o / 100; int t = o - 100 * j;
            W5fT[o] = W5[t * 200 + j];
        } else if (gid < 30000) {                // W6fT[j][t] = W6[t][j]
            int o = gid - 20000; int j = o / 100; int t = o - 100 * j;
            W6fT[o] = W6[t * 100 + j];
        } else if (gid < 50000) {                // W8fT[e][u] = W8[u][e]
            int o = gid - 30000; int e = o / 100; int u = o - 100 * e;
            W8fT[o] = W8[u * 200 + e];
        }
    } else {
        int gid = (b - 197) * 256 + tid;
        if (gid < L_) {
            float acc = 0.f;
            for (int u = 0; u < 100; u++) acc += b8[u] * le[u * 1000 + gid];
            bl8f[gid] = acc;
        } else if (gid < L_ + 100) {
            int u = gid - L_;
            float acc = 0.f;
            for (int t = 0; t < 100; t++) acc += b7[t] * W8[u * 200 + 100 + t];
            c8f[u] = acc;
        }
    }
}

// ---------------- K0d2: build W7b = split-bf16, MFMA-B-fragment layout ----------------
__global__ __launch_bounds__(256) void k0d2(const float* __restrict__ W7, const float* __restrict__ vvp,
                                            ushort* __restrict__ W7b) {
    int bc = blockIdx.x;
    int g = bc / 39, c = bc - 39 * g;
    int p0 = g * 1238 + c * 32;
    int pend = min(NPAIR, g * 1238 + 1238);
    ushort* dst = W7b + (size_t)bc * 8960;
    for (int idx = threadIdx.x; idx < 4480; idx += 256) {
        int n = idx / 40, k = idx - 40 * n;
        int p = p0 + k;
        float wv = 0.f;
        if (n < 100 && k < 32 && p < pend) wv = W7[n * NPAIR + p] * vvp[p];
        unsigned h, l;
        bfsplit(wv, h, l);
        dst[idx] = (ushort)h;
        dst[4480 + idx] = (ushort)l;
    }
}

// ---------------- K0e: build M = W8^T-fold @ le as split-bf16 B-fragments; blM ----------------
// M[e][l] = sum_u W8[u][e]*le[u][l].  Layout: Mb[lq 4][kc 7][hi/lo][n 256][40 k] ushort,
// n = l - lq*250 (pad n>=250 zero), k = e - kc*32 (pad e>=200 zero; k 32..39 never read).
// blM[l] = bl8f[l] + sum_u c8f[u]*le[u][l]  (folds b7 contribution through W8).
__global__ __launch_bounds__(256) void k0e(const float* __restrict__ W8fT, const float* __restrict__ le,
        const float* __restrict__ bl8f, const float* __restrict__ c8f,
        ushort* __restrict__ Mb, float* __restrict__ blM) {
    int b = blockIdx.x;
    int tid = threadIdx.x;
    if (b < 112) {
        __shared__ float ws8[800];           // [8 e][100 u]
        int lq = b / 28; int r = b - 28 * lq;
        int kc = r >> 2; int es = r & 3;
        int e0 = kc * 32 + es * 8;
        for (int idx = tid; idx < 800; idx += 256)
            ws8[idx] = (e0 * 100 + idx < 20000) ? W8fT[e0 * 100 + idx] : 0.f;
        __syncthreads();
        int n = tid;
        bool valid = (n < 250);
        int l = lq * 250 + n;
        float acc[8];
        #pragma unroll
        for (int m = 0; m < 8; m++) acc[m] = 0.f;
        for (int u = 0; u < 100; u++) {
            float lev = valid ? le[u * 1000 + l] : 0.f;
            #pragma unroll
            for (int m = 0; m < 8; m++) acc[m] = fmaf(ws8[m * 100 + u], lev, acc[m]);
        }
        unsigned h[8], lo[8];
        #pragma unroll
        for (int m = 0; m < 8; m++) bfsplit(acc[m], h[m], lo[m]);
        size_t base = (size_t)(lq * 7 + kc) * 20480;    // hi block of this (lq,kc)
        uint4 hv, lv;
        hv.x = h[0] | (h[1] << 16);  hv.y = h[2] | (h[3] << 16);
        hv.z = h[4] | (h[5] << 16);  hv.w = h[6] | (h[7] << 16);
        lv.x = lo[0] | (lo[1] << 16); lv.y = lo[2] | (lo[3] << 16);
        lv.z = lo[4] | (lo[5] << 16); lv.w = lo[6] | (lo[7] << 16);
        *(uint4*)(Mb + base + n * 40 + es * 8) = hv;
        *(uint4*)(Mb + base + 10240 + n * 40 + es * 8) = lv;
    } else {
        int gid = (b - 112) * 256 + tid;
        if (gid < L_) {
            float acc = bl8f[gid];
            for (int u = 0; u < 100; u++) acc = fmaf(c8f[u], le[u * 1000 + gid], acc);
            blM[gid] = acc;
        }
    }
}

// ---------------- K1: attention pools -> cat1[B][200] ----------------
__global__ __launch_bounds__(256) void k1(const float* __restrict__ x, const float* __restrict__ usf,
                                          const float* __restrict__ csf, float* __restrict__ cat1) {
    __shared__ float xs[N_ * 101];
    __shared__ float zs[2][64];
    __shared__ float wsm[2][64];
    __shared__ float uss[200];
    __shared__ float css[2];
    int b = blockIdx.x; int tid = threadIdx.x;
    const float* xr = x + (size_t)b * (N_ * E_);
    for (int li = tid; li < (N_ * E_) / 4; li += 256) {   // 1250 float4s
        float4 vv = ((const float4*)xr)[li];
        int flat = li * 4; int n = flat / 100; int e = flat - n * 100;
        float* d = xs + n * 101 + e;                       // e<=96, stays in row
        d[0] = vv.x; d[1] = vv.y; d[2] = vv.z; d[3] = vv.w;
    }
    if (tid < 200) uss[tid] = usf[tid];
    if (tid < 2) css[tid] = csf[tid];
    __syncthreads();
    if (tid < 100) {
        int h = (tid >= 50); int n = tid - 50 * h;
        float z = css[h];
        const float* u = uss + h * 100;
        for (int e = 0; e < 100; e++) z = fmaf(xs[n * 101 + e], u[e], z);
        zs[h][n] = expf(z);          // logits = exp(h @ W2^T)
    }
    __syncthreads();
    int wv = tid >> 6, ln = tid & 63;
    if (wv < 2) {
        float a = (ln < 50) ? zs[wv][ln] : -3.0e38f;
        float m = a;
        for (int s = 1; s < 64; s <<= 1) m = fmaxf(m, __shfl_xor(m, s, 64));
        float ex = (ln < 50) ? expf(a - m) : 0.f;
        float ss = ex;
        for (int s = 1; s < 64; s <<= 1) ss += __shfl_xor(ss, s, 64);
        if (ln < 50) wsm[wv][ln] = ex / ss;   // softmax over N
    }
    __syncthreads();
    if (tid < 200) {
        int h = (tid >= 100); int e = tid - 100 * h;
        float q = 0.f;
        for (int n = 0; n < 50; n++) q = fmaf(xs[n * 101 + e], wsm[h][n], q);
        cat1[(size_t)b * 200 + tid] = q;      // [q1 | q2]
    }
}

// ---------------- K2: h5, h6 (vector) + h7 via MFMA split-bf16 (round-5, unchanged) -------
__global__ __launch_bounds__(1024, 4) void k2(const float* __restrict__ cat1,
        const float* __restrict__ W5fT, const float* __restrict__ W6fT,
        const float* __restrict__ b5f, const float* __restrict__ b6f,
        const ushort* __restrict__ W7b, const int* __restrict__ pairIJ,
        float* __restrict__ h6T, float* __restrict__ h7Tp) {
    __shared__ float sbuf[128 * 101];                  // cat1 half-tile, then h5 tile
    __shared__ __align__(16) ushort scratch2[28672];   // A/B dbuf scratch
    __shared__ int pijc2[2][32];
    const int g  = blockIdx.x >> 6;          // pair group 0..3
    const int rb = blockIdx.x & 63;
    const int r0 = rb * 128;
    const int tid = threadIdx.x;
    const int lane = tid & 63;
    const int w = tid >> 6;                  // 0..15
    const int wk = w & 3;
    const int kbase = (wk < 3) ? wk * 28 : 72;
    const int pg = (w >> 2) & 1;             // j parity
    const int rh = (w >> 3) & 1;             // row half
    const int rowA = rh * 64 + lane;
    const int hbA = rowA * 101;
    const int mt = w >> 1;                   // M-tile 0..7
    const int nh = w & 1;                    // N-half
    float* wchA0 = (float*)scratch2;
    float* wchA1 = wchA0 + 6400;
    float* wchf  = wchA0;

    float acc[28];

    // phase A: h5 = cat1 @ W5^T + b5
    if (pg == 0) {
        const float4* bp = (const float4*)(b5f + kbase);
        #pragma unroll
        for (int q = 0; q < 7; q++) {
            float4 t = bp[q];
            acc[4*q] = t.x; acc[4*q+1] = t.y; acc[4*q+2] = t.z; acc[4*q+3] = t.w;
        }
    } else {
        #pragma unroll
        for (int m = 0; m < 28; m++) acc[m] = 0.f;
    }
    for (int half = 0; half < 2; half++) {
        const float* Wg = W5fT + half * 10000;
        for (int o = tid; o < 3200; o += 1024) {
            int r = o / 25; int c = o - r * 25;
            float4 v = ((const float4*)(cat1 + (size_t)(r0 + r) * 200 + half * 100))[c];
            float* d = sbuf + r * 101 + c * 4;
            d[0] = v.x; d[1] = v.y; d[2] = v.z; d[3] = v.w;
        }
        {
            const float4* src4 = (const float4*)Wg;
            #pragma unroll
            for (int k = 0; k < 2; k++) {
                int o = tid + (k << 10);
                if (o < 1600) ((float4*)wchA0)[o] = src4[o];
            }
        }
        __syncthreads();
        int cur = 0;
        for (int c2 = 0; c2 < 2; c2++) {
            int rbase = c2 << 6;
            int rc = c2 ? 36 : 64;
            float4 stg; int nf4n = c2 ? 0 : 900;
            { int o = tid; if (o < nf4n) stg = ((const float4*)(Wg + 6400))[o]; }
            const float* wb = cur ? wchA1 : wchA0;
            for (int jj = pg; jj < rc; jj += 2) {
                float s = sbuf[hbA + rbase + jj];
                const float4* wl = (const float4*)(wb + jj * 100 + kbase);
                #pragma unroll
                for (int q = 0; q < 7; q++) {
                    float4 wv = wl[q];
                    acc[4*q]   = fmaf(s, wv.x, acc[4*q]);
                    acc[4*q+1] = fmaf(s, wv.y, acc[4*q+1]);
                    acc[4*q+2] = fmaf(s, wv.z, acc[4*q+2]);
                    acc[4*q+3] = fmaf(s, wv.w, acc[4*q+3]);
                }
            }
            { int o = tid; if (o < nf4n) ((float4*)(cur ? wchA0 : wchA1))[o] = stg; }
            __syncthreads();
            cur ^= 1;
        }
    }
    #pragma unroll 1
    for (int R = 0; R < 2; R++) {
        if (pg == 1 && rh == R) {
            float* d = wchf + (wk * 64 + lane) * 28;
            #pragma unroll
            for (int m = 0; m < 28; m++) d[m] = acc[m];
        }
        __syncthreads();
        if (pg == 0 && rh == R) {
            const float* d = wchf + (wk * 64 + lane) * 28;
            #pragma unroll
            for (int m = 0; m < 28; m++) acc[m] += d[m];
            #pragma unroll
            for (int m = 0; m < 28; m++) sbuf[hbA + kbase + m] = acc[m];
        }
        __syncthreads();
    }

    // phase B: h6 k-slice [g*25, g*25+25)
    {
        const int k0g = g * 25 + ((wk < 3) ? wk * 7 : 18);
        float accB[7];
        if (pg == 0) {
            #pragma unroll
            for (int m = 0; m < 7; m++) accB[m] = b6f[k0g + m];
        } else {
            #pragma unroll
            for (int m = 0; m < 7; m++) accB[m] = 0.f;
        }
        {
            const float4* src4 = (const float4*)W6fT;
            #pragma unroll
            for (int k = 0; k < 2; k++) {
                int o = tid + (k << 10);
                if (o < 1600) ((float4*)wchA0)[o] = src4[o];
            }
        }
        __syncthreads();
        int cur = 0;
        for (int c2 = 0; c2 < 2; c2++) {
            int rbase = c2 << 6;
            int rc = c2 ? 36 : 64;
            float4 stg; int nf4n = c2 ? 0 : 900;
            { int o = tid; if (o < nf4n) stg = ((const float4*)(W6fT + 6400))[o]; }
            const float* wb = cur ? wchA1 : wchA0;
            for (int jj = pg; jj < rc; jj += 2) {
                float s = sbuf[hbA + rbase + jj];
                const float* wl = wb + jj * 100 + k0g;
                #pragma unroll
                for (int m = 0; m < 7; m++) accB[m] = fmaf(s, wl[m], accB[m]);
            }
            { int o = tid; if (o < nf4n) ((float4*)(cur ? wchA0 : wchA1))[o] = stg; }
            __syncthreads();
            cur ^= 1;
        }
        #pragma unroll 1
        for (int R = 0; R < 2; R++) {
            if (pg == 1 && rh == R) {
                float* d = wchf + (wk * 64 + lane) * 7;
                #pragma unroll
                for (int m = 0; m < 7; m++) d[m] = accB[m];
            }
            __syncthreads();
            if (pg == 0 && rh == R) {
                const float* d = wchf + (wk * 64 + lane) * 7;
                #pragma unroll
                for (int m = 0; m < 7; m++) accB[m] += d[m];
                #pragma unroll
                for (int m = 0; m < 7; m++)
                    h6T[(size_t)(k0g + m) * B_ + r0 + rowA] = accB[m];
            }
            __syncthreads();
        }
    }

    // phase C: h7 = cf @ W7' via MFMA (split-bf16)
    const int pstart = g * 1238;
    const int pend = min(NPAIR, pstart + 1238);
    const ushort* W7g = W7b + (size_t)(g * 39) * 8960;
    ushort* Ach = scratch2;            // [8][16][40]
    ushort* Acl = scratch2 + 5120;
    ushort* Bb0 = scratch2 + 10240;    // [2][112][40] per chunk, dbuf
    ushort* Bb1 = scratch2 + 19200;
    {
        const float4* src = (const float4*)W7g;
        for (int o = tid; o < 1120; o += 1024) ((float4*)Bb0)[o] = src[o];
        if (tid < 32) { int p = pstart + tid; pijc2[0][tid] = (p < pend) ? pairIJ[p] : 1; }
    }
    __syncthreads();
    f32x4 accv[4];
    #pragma unroll
    for (int q = 0; q < 4; q++) accv[q] = (f32x4){0.f, 0.f, 0.f, 0.f};
    int cur = 0;
    const int lm = lane & 15;
    const int lko = (lane >> 4) << 3;
    const int p2 = (tid & 15) * 2;
    const int rb2 = (tid >> 4) * 2;
    for (int c = 0; c < 39; c++) {
        float4 s0, s1; int pvN = 1;
        if (c < 38) {
            const float4* src = (const float4*)(W7g + (size_t)(c + 1) * 8960);
            s0 = src[tid];
            if (tid < 96) s1 = src[tid + 1024];
            if (tid < 32) { int p = pstart + (c + 1) * 32 + tid; pvN = (p < pend) ? pairIJ[p] : 1; }
        }
        {
            int ij0 = pijc2[cur][p2];
            int ij1 = pijc2[cur][p2 + 1];
            int i0 = ij0 >> 8, j0 = ij0 & 255;
            int i1 = ij1 >> 8, j1 = ij1 & 255;
            #pragma unroll
            for (int rr = 0; rr < 2; rr++) {
                int r = rb2 + rr;
                const float* hr = sbuf + r * 101;
                float a0 = hr[i0] * hr[j0];
                float a1 = hr[i1] * hr[j1];
                unsigned h0, l0, h1, l1;
                bfsplit(a0, h0, l0);
                bfsplit(a1, h1, l1);
                int idx = (r >> 4) * 640 + (r & 15) * 40 + p2;
                *(unsigned*)(Ach + idx) = h0 | (h1 << 16);
                *(unsigned*)(Acl + idx) = l0 | (l1 << 16);
            }
        }
        __syncthreads();
        {
            const ushort* Bc = cur ? Bb1 : Bb0;
            int ab = mt * 640 + lm * 40 + lko;
            short8v aH = *(const short8v*)(Ach + ab);
            short8v aL = *(const short8v*)(Acl + ab);
            #pragma unroll
            for (int q = 0; q < 4; q++) {
                if (!(nh && q == 3)) {
                    int nt = nh * 4 + q;
                    const ushort* bp = Bc + (nt * 16 + lm) * 40 + lko;
                    short8v bH = *(const short8v*)bp;
                    short8v bL = *(const short8v*)(bp + 4480);
                    accv[q] = __builtin_amdgcn_mfma_f32_16x16x32_bf16(aH, bH, accv[q], 0, 0, 0);
                    accv[q] = __builtin_amdgcn_mfma_f32_16x16x32_bf16(aH, bL, accv[q], 0, 0, 0);
                    accv[q] = __builtin_amdgcn_mfma_f32_16x16x32_bf16(aL, bH, accv[q], 0, 0, 0);
                }
            }
        }
        if (c < 38) {
            ushort* Bn = cur ? Bb0 : Bb1;
            ((float4*)Bn)[tid] = s0;
            if (tid < 96) ((float4*)Bn)[tid + 1024] = s1;
            if (tid < 32) pijc2[cur ^ 1][tid] = pvN;
        }
        __syncthreads();
        cur ^= 1;
    }
    {
        float* h7p = h7Tp + (size_t)g * 100 * B_;
        int rowb = r0 + mt * 16 + ((lane >> 4) << 2);
        #pragma unroll
        for (int q = 0; q < 4; q++) {
            if (!(nh && q == 3)) {
                int col = (nh * 4 + q) * 16 + lm;
                if (col < 100) {
                    float4 o4;
                    o4.x = accv[q][0]; o4.y = accv[q][1]; o4.z = accv[q][2]; o4.w = accv[q][3];
                    *(float4*)(h7p + (size_t)col * B_ + rowb) = o4;
                }
            }
        }
    }
}

// ---------------- K3: out = [h6 | h7sum] @ M + blM  (replaces k3a+k3b) ----------------
// GEMM [8192x200]@[200x1000] via split-bf16 MFMA. Grid 256 = 64 b-tiles(128) x 4 l-quarters(250).
// 1024 thr = 16 waves: (mtp=w&3 -> 2 m-tiles), (nq=w>>2 -> 4 n-tiles). K=200 in 7 chunks of 32.
// FIX vs round 6: each Mb chunk is 2560 float4 (hi 1280 + lo 1280); round 6 staged only 1280,
// leaving the bL half of Bb as uninitialized LDS -> 6e-2 absmax. Now s0+s1+s2 stage all 2560.
__global__ __launch_bounds__(1024, 4) void k3(const float* __restrict__ h6T,
        const float* __restrict__ h7Tp, const float* __restrict__ Mbf,
        const float* __restrict__ blM, float* __restrict__ out) {
    __shared__ __align__(16) ushort Bb[20480];  // hi[256][40] | lo[256][40]
    __shared__ __align__(16) ushort Ab[10240];  // hi[128][40] | lo[128][40]
    const int lq = blockIdx.x & 3;
    const int r0 = (blockIdx.x >> 2) * 128;
    const int tid = threadIdx.x;
    const int lane = tid & 63;
    const int w = tid >> 6;
    const int mtp = w & 3;
    const int nq = w >> 2;
    const int lm = lane & 15;
    const int lko = (lane >> 4) << 3;
    const float4* Msrc = (const float4*)Mbf;
    f32x4 acc[2][4];
    #pragma unroll
    for (int mi = 0; mi < 2; mi++)
        #pragma unroll
        for (int ni = 0; ni < 4; ni++) acc[mi][ni] = (f32x4){0.f, 0.f, 0.f, 0.f};

    for (int kc = 0; kc < 7; kc++) {
        // issue-early: B chunk (2560 f4 = hi+lo) + A sources into regs
        float4 s0, s1, s2;
        const float4* bsrc = Msrc + (lq * 7 + kc) * 2560;
        s0 = bsrc[tid];
        s1 = bsrc[1024 + tid];
        if (tid < 512) s2 = bsrc[2048 + tid];
        float av[4];
        #pragma unroll
        for (int j = 0; j < 4; j++) {
            int idx = tid + (j << 10);
            int r = idx & 127; int kk = idx >> 7;
            int e = kc * 32 + kk;
            float vv2 = 0.f;
            if (e < 100) {
                vv2 = h6T[(size_t)e * B_ + r0 + r];
            } else if (e < 200) {
                int ee = e - 100;
                vv2 = h7Tp[(size_t)ee * B_ + r0 + r]
                    + h7Tp[(size_t)(100 + ee) * B_ + r0 + r]
                    + h7Tp[(size_t)(200 + ee) * B_ + r0 + r]
                    + h7Tp[(size_t)(300 + ee) * B_ + r0 + r];
            }
            av[j] = vv2;
        }
        __syncthreads();        // prior chunk's MFMA reads done
        ((float4*)Bb)[tid] = s0;
        ((float4*)Bb)[1024 + tid] = s1;
        if (tid < 512) ((float4*)Bb)[2048 + tid] = s2;
        #pragma unroll
        for (int j = 0; j < 4; j++) {
            int idx = tid + (j << 10);
            int r = idx & 127; int kk = idx >> 7;
            unsigned hh, ll;
            bfsplit(av[j], hh, ll);
            Ab[r * 40 + kk] = (ushort)hh;
            Ab[5120 + r * 40 + kk] = (ushort)ll;
        }
        __syncthreads();
        // MFMA: 2 m-tiles x 4 n-tiles x 3 terms
        short8v aH[2], aL[2];
        #pragma unroll
        for (int mi = 0; mi < 2; mi++) {
            int ao = ((mtp * 2 + mi) * 16 + lm) * 40 + lko;
            aH[mi] = *(const short8v*)(Ab + ao);
            aL[mi] = *(const short8v*)(Ab + 5120 + ao);
        }
        #pragma unroll
        for (int ni = 0; ni < 4; ni++) {
            int nt = nq * 4 + ni;
            int bo = (nt * 16 + lm) * 40 + lko;
            short8v bH = *(const short8v*)(Bb + bo);
            short8v bL = *(const short8v*)(Bb + 10240 + bo);
            #pragma unroll
            for (int mi = 0; mi < 2; mi++) {
                acc[mi][ni] = __builtin_amdgcn_mfma_f32_16x16x32_bf16(aL[mi], bH, acc[mi][ni], 0, 0, 0);
                acc[mi][ni] = __builtin_amdgcn_mfma_f32_16x16x32_bf16(aH[mi], bL, acc[mi][ni], 0, 0, 0);
                acc[mi][ni] = __builtin_amdgcn_mfma_f32_16x16x32_bf16(aH[mi], bH, acc[mi][ni], 0, 0, 0);
            }
        }
    }
    // epilogue: out[b][l] = acc + blM[l]
    #pragma unroll
    for (int ni = 0; ni < 4; ni++) {
        int n = nq * 64 + ni * 16 + lm;
        bool valid = (n < 250);
        int l = lq * 250 + (valid ? n : 0);
        float blm = blM[l];
        #pragma unroll
        for (int mi = 0; mi < 2; mi++) {
            int b0 = r0 + (mtp * 2 + mi) * 16 + ((lane >> 4) << 2);
            if (valid) {
                #pragma unroll
                for (int q = 0; q < 4; q++)
                    out[(size_t)(b0 + q) * 1000 + l] = acc[mi][ni][q] + blm;
            }
        }
    }
}

extern "C" void kernel_launch(void* const* d_in, const int* in_sizes, int n_in,
                              void* d_out, int out_size, void* d_ws, size_t ws_size,
                              hipStream_t stream) {
    const float* x  = (const float*)d_in[0];
    const float* v  = (const float*)d_in[1];
    const float* W1 = (const float*)d_in[2];
    const float* b1 = (const float*)d_in[3];
    const float* W2 = (const float*)d_in[4];
    const float* W3 = (const float*)d_in[5];
    const float* b3 = (const float*)d_in[6];
    const float* W4 = (const float*)d_in[7];
    const float* W5 = (const float*)d_in[8];
    const float* b5 = (const float*)d_in[9];
    const float* W6 = (const float*)d_in[10];
    const float* b6 = (const float*)d_in[11];
    const float* W7 = (const float*)d_in[12];
    const float* b7 = (const float*)d_in[13];
    const float* W8 = (const float*)d_in[14];
    const float* b8 = (const float*)d_in[15];
    const float* le = (const float*)d_in[16];
    float* out = (float*)d_out;
    float* ws = (float*)d_ws;

    float* cat1   = ws;                 // 1,638,400
    float* h6T    = ws + 1638400;       //   819,200
    float* h7Tp   = ws + 2457600;       // 3,276,800 (4 partials x 100 x B)
    float* h8Tslot= ws + 5734400;       //   819,200  (aliased by W7b)
    float* Mslot  = ws + 6553600;       //   495,000 free slot: Mb (286,720 f32) + blM (1,000)
    float* W5fT   = ws + 7048600;       //    20,000
    float* W6fT   = ws + 7068600;       //    10,000
    float* W8fT   = ws + 7078600;       //    20,000
    float* usf    = ws + 7098600;       //       200
    float* csf    = ws + 7098800;       //       2 (+2 pad)
    float* b5f    = ws + 7098804;       //       100
    float* b6f    = ws + 7098904;       //       100
    // ws + 7099004: 100 free (old b7f)
    float* bl8f   = ws + 7099104;       //      1000
    float* vvp    = ws + 7100104;       //      4950
    int*   pairIJ = (int*)(ws + 7105054); //    4950
    float* c8f    = ws + 7110004;       //       100

    ushort* W7b   = (ushort*)h8Tslot;   // 1,397,760 ushort <= 819,200 f32; dead before/after k2
    ushort* Mb    = (ushort*)Mslot;     // 573,440 ushort = 286,720 f32
    float*  blM   = Mslot + 286720;     // 1,000 f32

    k0<<<202, 256, 0, stream>>>(v, W1, b1, W2, W3, b3, W4, W5, W6, W8, b5, b6, b7, b8, le,
                                usf, csf, b5f, b6f, vvp, pairIJ,
                                W5fT, W6fT, W8fT, bl8f, c8f);
    k0d2<<<156, 256, 0, stream>>>(W7, vvp, W7b);
    k0e<<<116, 256, 0, stream>>>(W8fT, le, bl8f, c8f, Mb, blM);
    k1<<<8192, 256, 0, stream>>>(x, usf, csf, cat1);
    k2<<<256, 1024, 0, stream>>>(cat1, W5fT, W6fT, b5f, b6f, W7b, pairIJ, h6T, h7Tp);
    k3<<<256, 1024, 0, stream>>>(h6T, h7Tp, (const float*)Mb, blM, out);
}